// Round 2
// baseline (426.839 us; speedup 1.0000x reference)
//
#include <hip/hip_runtime.h>
#include <hip/hip_bf16.h>

typedef __attribute__((ext_vector_type(8))) __bf16 bf16x8;
typedef __attribute__((ext_vector_type(4))) __bf16 bf16x4;
typedef __attribute__((ext_vector_type(4))) float f32x4;

#define N_TOK 8192
#define IN_FEAT 2048
#define D1 512
#define D2 128

__device__ __forceinline__ void gload_lds16(const __bf16* g, __bf16* l) {
    __builtin_amdgcn_global_load_lds(
        (const __attribute__((address_space(1))) void*)g,
        (__attribute__((address_space(3))) void*)l,
        16, 0, 0);
}

// ---------------------------------------------------------------------------
// Cast f32 -> bf16, 4 elements/thread
// ---------------------------------------------------------------------------
__global__ void cast_k(const float* __restrict__ in, __bf16* __restrict__ out, int n4) {
    int i = blockIdx.x * blockDim.x + threadIdx.x;
    if (i < n4) {
        float4 v = ((const float4*)in)[i];
        bf16x4 o;
        o[0] = (__bf16)v.x; o[1] = (__bf16)v.y; o[2] = (__bf16)v.z; o[3] = (__bf16)v.w;
        ((bf16x4*)out)[i] = o;
    }
}

// ---------------------------------------------------------------------------
// wksum[c] = sum_o Wk[o,c]   (Wk is (D2,D2) row-major (o,c))
// ---------------------------------------------------------------------------
__global__ void wksum_k(const float* __restrict__ Wk, float* __restrict__ wksum) {
    int c = threadIdx.x;
    if (c < D2) {
        float s = 0.0f;
        for (int o = 0; o < D2; ++o) s += Wk[o * D2 + c];
        wksum[c] = s;
    }
}

// ---------------------------------------------------------------------------
// kb[n,c] = bf16( wksum[c] * h2[n,c] + bk[c] )
// NOTE: reference einsum "oc,bcn->bcn" keeps c elementwise and sums over o —
// k is a column-scale of h2, NOT a projection.
// ---------------------------------------------------------------------------
__global__ __launch_bounds__(256)
void make_k(const __bf16* __restrict__ h2b, const float* __restrict__ wksum,
            const float* __restrict__ bk, __bf16* __restrict__ kb, int n4) {
    int i = blockIdx.x * blockDim.x + threadIdx.x;
    if (i < n4) {
        bf16x4 h = ((const bf16x4*)h2b)[i];
        int c0 = (i * 4) & (D2 - 1);
        bf16x4 o;
#pragma unroll
        for (int j = 0; j < 4; ++j)
            o[j] = (__bf16)((float)h[j] * wksum[c0 + j] + bk[c0 + j]);
        ((bf16x4*)kb)[i] = o;
    }
}

// ---------------------------------------------------------------------------
// gemm_bt: C[m,n] = sum_k A[m,k] * B[n,k]   (B stored transposed, row-major (N,K))
// 128x128 tile, BK=32, 4 waves (2x2), 16x16x32 bf16 MFMA, 4x4 frags/wave.
// AF32: A is f32 in global, reg-staged + converted to bf16 in LDS.
// EPI: 0 = plain f32 store (no bias); 1 = bias+relu -> bf16; 3 = bias -> bf16
// ---------------------------------------------------------------------------
template<bool AF32, int EPI>
__global__ __launch_bounds__(256)
void gemm_bt(const void* __restrict__ Av, const __bf16* __restrict__ B,
             const float* __restrict__ bias, void* __restrict__ Cv,
             int M, int N, int K)
{
    __shared__ __bf16 lA[128 * 32];
    __shared__ __bf16 lB[128 * 32];

    const int t    = threadIdx.x;
    const int lane = t & 63;
    const int w    = t >> 6;          // wave id 0..3
    const int wr   = w >> 1;          // wave row (0..1)
    const int wc   = w & 1;           // wave col (0..1)
    const int m0   = blockIdx.y * 128;
    const int n0   = blockIdx.x * 128;

    const int rS = w * 16 + (lane >> 2);      // 0..63
    const int cS = (lane & 3) * 8;

    const int fr = lane & 15;                 // fragment row/col
    const int ko = (lane >> 4) * 8;           // k offset within BK
    const int rj = (lane >> 4) * 4;           // C/D row base

    f32x4 acc[4][4] = {};

    for (int k0 = 0; k0 < K; k0 += 32) {
        if constexpr (AF32) {
            const float* Af = (const float*)Av;
            float4 regs[4];
#pragma unroll
            for (int i = 0; i < 4; ++i) {
                int r = i * 32 + (t >> 3);
                regs[i] = *(const float4*)&Af[(size_t)(m0 + r) * K + k0 + (t & 7) * 4];
            }
            __syncthreads();   // previous tile fully consumed
#pragma unroll
            for (int i = 0; i < 4; ++i) {
                int r = i * 32 + (t >> 3);
                bf16x4 o;
                o[0] = (__bf16)regs[i].x; o[1] = (__bf16)regs[i].y;
                o[2] = (__bf16)regs[i].z; o[3] = (__bf16)regs[i].w;
                *(bf16x4*)&lA[r * 32 + (t & 7) * 4] = o;
            }
            gload_lds16(B + (size_t)(n0 + rS) * K + k0 + cS, lB + w * 512);
            gload_lds16(B + (size_t)(n0 + 64 + rS) * K + k0 + cS, lB + 2048 + w * 512);
            __syncthreads();   // drains vmcnt+lgkmcnt: tiles ready
        } else {
            const __bf16* Ab = (const __bf16*)Av;
            __syncthreads();   // previous tile fully consumed
            gload_lds16(Ab + (size_t)(m0 + rS) * K + k0 + cS, lA + w * 512);
            gload_lds16(Ab + (size_t)(m0 + 64 + rS) * K + k0 + cS, lA + 2048 + w * 512);
            gload_lds16(B + (size_t)(n0 + rS) * K + k0 + cS, lB + w * 512);
            gload_lds16(B + (size_t)(n0 + 64 + rS) * K + k0 + cS, lB + 2048 + w * 512);
            __syncthreads();   // tiles ready
        }

        bf16x8 af[4], bfr[4];
#pragma unroll
        for (int m = 0; m < 4; ++m)
            af[m] = *(const bf16x8*)&lA[(wr * 64 + m * 16 + fr) * 32 + ko];
#pragma unroll
        for (int n = 0; n < 4; ++n)
            bfr[n] = *(const bf16x8*)&lB[(wc * 64 + n * 16 + fr) * 32 + ko];
#pragma unroll
        for (int m = 0; m < 4; ++m)
#pragma unroll
            for (int n = 0; n < 4; ++n)
                acc[m][n] = __builtin_amdgcn_mfma_f32_16x16x32_bf16(af[m], bfr[n], acc[m][n], 0, 0, 0);
    }

    // epilogue: C/D layout col = lane&15, row = (lane>>4)*4 + j
    if constexpr (EPI == 0) {
        float* C = (float*)Cv;
#pragma unroll
        for (int m = 0; m < 4; ++m) {
            int row = m0 + wr * 64 + m * 16 + rj;
#pragma unroll
            for (int n = 0; n < 4; ++n) {
                int col = n0 + wc * 64 + n * 16 + fr;
#pragma unroll
                for (int j = 0; j < 4; ++j)
                    C[(size_t)(row + j) * N + col] = acc[m][n][j];
            }
        }
    } else {
        __bf16* C = (__bf16*)Cv;
#pragma unroll
        for (int n = 0; n < 4; ++n) {
            int col = n0 + wc * 64 + n * 16 + fr;
            float bv = bias[col];
#pragma unroll
            for (int m = 0; m < 4; ++m) {
                int row = m0 + wr * 64 + m * 16 + rj;
#pragma unroll
                for (int j = 0; j < 4; ++j) {
                    float v = acc[m][n][j] + bv;
                    if constexpr (EPI == 1) v = fmaxf(v, 0.0f);
                    C[(size_t)(row + j) * N + col] = (__bf16)v;
                }
            }
        }
    }
}

// ---------------------------------------------------------------------------
// Row softmax (in place): p = exp(e - rowmax), store p; invsum[n] = 1/sum(p)
// ---------------------------------------------------------------------------
__device__ __forceinline__ float waveMax(float v) {
#pragma unroll
    for (int o = 32; o > 0; o >>= 1) v = fmaxf(v, __shfl_xor(v, o));
    return v;
}
__device__ __forceinline__ float waveSum(float v) {
#pragma unroll
    for (int o = 32; o > 0; o >>= 1) v += __shfl_xor(v, o);
    return v;
}

__global__ __launch_bounds__(256)
void softmax_rows(float* __restrict__ e, float* __restrict__ invsum) {
    __shared__ float red[4];
    int n = blockIdx.x, t = threadIdx.x;
    float2* row = (float2*)(e + (size_t)n * N_TOK);

    float m = -1e30f;
    for (int i = t; i < N_TOK / 2; i += 256) {
        float2 v = row[i];
        m = fmaxf(m, fmaxf(v.x, v.y));
    }
    m = waveMax(m);
    if ((t & 63) == 0) red[t >> 6] = m;
    __syncthreads();
    m = fmaxf(fmaxf(red[0], red[1]), fmaxf(red[2], red[3]));
    __syncthreads();

    float s = 0.0f;
    for (int i = t; i < N_TOK / 2; i += 256) {
        float2 v = row[i];
        v.x = __expf(v.x - m);
        v.y = __expf(v.y - m);
        row[i] = v;
        s += v.x + v.y;
    }
    s = waveSum(s);
    if ((t & 63) == 0) red[t >> 6] = s;
    __syncthreads();
    if (t == 0) invsum[n] = 1.0f / (red[0] + red[1] + red[2] + red[3]);
}

// ---------------------------------------------------------------------------
// attn = p * invsum[row] (in place) + column-sum accumulation into colw
// ---------------------------------------------------------------------------
__global__ __launch_bounds__(256)
void normalize_colsum(float* __restrict__ e, const float* __restrict__ invsum,
                      float* __restrict__ colw) {
    int c  = blockIdx.x * 256 + threadIdx.x;
    int r0 = blockIdx.y * 512;
    float acc = 0.0f;
    for (int r = r0; r < r0 + 512; ++r) {
        size_t idx = (size_t)r * N_TOK + c;
        float v = e[idx] * invsum[r];
        e[idx] = v;
        acc += v;
    }
    atomicAdd(&colw[c], acc);
}

// ---------------------------------------------------------------------------
// xw[c] = sum_m colw[m]*h2[m,c] ; xh[c] = sum_m h2[m,c]
// ---------------------------------------------------------------------------
__global__ __launch_bounds__(256)
void reduce_x2(const __bf16* __restrict__ h2b, const float* __restrict__ colw,
               float* __restrict__ xw, float* __restrict__ xh) {
    int b = blockIdx.x, t = threadIdx.x;
    int c = t & 127, half = t >> 7;
    float aw = 0.0f, ah = 0.0f;
    for (int m = b * 128 + half; m < (b + 1) * 128; m += 2) {
        float h  = (float)h2b[(size_t)m * D2 + c];
        float wv = colw[m];
        aw += wv * h;
        ah += h;
    }
    atomicAdd(&xw[c], aw);
    atomicAdd(&xh[c], ah);
}

__global__ void logits_k(const float* __restrict__ xw, const float* __restrict__ xh,
                         const float* __restrict__ gamma, const float* __restrict__ W3,
                         const float* __restrict__ b3, float* __restrict__ out) {
    __shared__ float x2[D2];
    int t = threadIdx.x;
    float g = gamma[0];
    if (t < D2) x2[t] = (g * xw[t] + xh[t]) * (1.0f / (float)N_TOK);
    __syncthreads();
    if (t < 10) {
        float s = b3[t];
        for (int c = 0; c < D2; ++c) s += x2[c] * W3[t * D2 + c];
        out[t] = s;
    }
}

__global__ void zero_acc(float* __restrict__ colw, float* __restrict__ xw,
                         float* __restrict__ xh) {
    int t = blockIdx.x * 256 + threadIdx.x;
    if (t < N_TOK) colw[t] = 0.0f;
    if (t < D2) { xw[t] = 0.0f; xh[t] = 0.0f; }
}

// ---------------------------------------------------------------------------
extern "C" void kernel_launch(void* const* d_in, const int* in_sizes, int n_in,
                              void* d_out, int out_size, void* d_ws, size_t ws_size,
                              hipStream_t stream) {
    const float* x     = (const float*)d_in[0];
    const float* W1    = (const float*)d_in[1];
    const float* b1    = (const float*)d_in[2];
    const float* W2    = (const float*)d_in[3];
    const float* b2    = (const float*)d_in[4];
    const float* Wq    = (const float*)d_in[5];
    const float* bq    = (const float*)d_in[6];
    const float* Wk    = (const float*)d_in[7];
    const float* bk    = (const float*)d_in[8];
    const float* gamma = (const float*)d_in[9];
    const float* W3    = (const float*)d_in[10];
    const float* b3    = (const float*)d_in[11];

    float* out  = (float*)d_out;
    float* attn = out + 10;            // 8192x8192 f32

    char* p = (char*)d_ws;
    __bf16* w1b = (__bf16*)p; p += (size_t)D1 * IN_FEAT * 2;   // 2 MB
    __bf16* w2b = (__bf16*)p; p += (size_t)D2 * D1 * 2;        // 128 KB
    __bf16* wqb = (__bf16*)p; p += (size_t)D2 * D2 * 2;        // 32 KB
    __bf16* h1b = (__bf16*)p; p += (size_t)N_TOK * D1 * 2;     // 8 MB
    __bf16* h2b = (__bf16*)p; p += (size_t)N_TOK * D2 * 2;     // 2 MB
    __bf16* qb  = (__bf16*)p; p += (size_t)N_TOK * D2 * 2;     // 2 MB
    __bf16* kb  = (__bf16*)p; p += (size_t)N_TOK * D2 * 2;     // 2 MB
    float* invsum = (float*)p; p += N_TOK * 4;
    float* colw   = (float*)p; p += N_TOK * 4;
    float* wksum  = (float*)p; p += D2 * 4;
    float* xw     = (float*)p; p += D2 * 4;
    float* xh     = (float*)p; p += D2 * 4;

    zero_acc<<<32, 256, 0, stream>>>(colw, xw, xh);
    cast_k<<<1024, 256, 0, stream>>>(W1, w1b, D1 * IN_FEAT / 4);
    cast_k<<<64,   256, 0, stream>>>(W2, w2b, D2 * D1 / 4);
    cast_k<<<16,   256, 0, stream>>>(Wq, wqb, D2 * D2 / 4);
    wksum_k<<<1, 128, 0, stream>>>(Wk, wksum);

    // h1 = relu(x @ W1^T + b1)   [8192,512]
    gemm_bt<true, 1><<<dim3(D1 / 128, N_TOK / 128), 256, 0, stream>>>(
        x, w1b, b1, h1b, N_TOK, D1, IN_FEAT);
    // h2 = relu(h1 @ W2^T + b2)  [8192,128]
    gemm_bt<false, 1><<<dim3(D2 / 128, N_TOK / 128), 256, 0, stream>>>(
        h1b, w2b, b2, h2b, N_TOK, D2, D1);
    // q = h2 @ Wq^T + bq  [8192,128]
    gemm_bt<false, 3><<<dim3(D2 / 128, N_TOK / 128), 256, 0, stream>>>(
        h2b, wqb, bq, qb, N_TOK, D2, D2);
    // k'[n,c] = wksum[c]*h2[n,c] + bk[c]   (elementwise column scale!)
    make_k<<<1024, 256, 0, stream>>>(h2b, wksum, bk, kb, N_TOK * D2 / 4);
    // energy = q @ k'^T  [8192,8192] f32 into d_out+10
    gemm_bt<false, 0><<<dim3(N_TOK / 128, N_TOK / 128), 256, 0, stream>>>(
        qb, kb, nullptr, attn, N_TOK, N_TOK, D2);

    softmax_rows<<<N_TOK, 256, 0, stream>>>(attn, invsum);
    normalize_colsum<<<dim3(32, 16), 256, 0, stream>>>(attn, invsum, colw);
    reduce_x2<<<64, 256, 0, stream>>>(h2b, colw, xw, xh);
    logits_k<<<1, 128, 0, stream>>>(xw, xh, gamma, W3, b3, out);
}

// Round 4
// 323.763 us; speedup vs baseline: 1.3184x; 1.3184x over previous
//
#include <hip/hip_runtime.h>
#include <hip/hip_bf16.h>

typedef __attribute__((ext_vector_type(8))) __bf16 bf16x8;
typedef __attribute__((ext_vector_type(4))) __bf16 bf16x4;
typedef __attribute__((ext_vector_type(4))) float f32x4;

#define N_TOK 8192
#define IN_FEAT 2048
#define D1 512
#define D2 128
#define QBLK 128
#define KCHUNK 1024
#define KTILE 128
#define NKC (N_TOK / KCHUNK)   // 8
#define NQB (N_TOK / QBLK)     // 64

__device__ __forceinline__ void gload_lds16(const __bf16* g, __bf16* l) {
    __builtin_amdgcn_global_load_lds(
        (const __attribute__((address_space(1))) void*)g,
        (__attribute__((address_space(3))) void*)l,
        16, 0, 0);
}

// ---------------------------------------------------------------------------
// Stage a 128x128 bf16 tile (rows of 256B) global->LDS, linear LDS dest,
// XOR-swizzled SOURCE (chunk ^= row&7) so swizzled reads land right (rule 21).
// ---------------------------------------------------------------------------
__device__ __forceinline__ void stage_tile(const __bf16* __restrict__ g,
                                           __bf16* lds, int w, int lane) {
#pragma unroll
    for (int i = 0; i < 8; ++i) {
        int row   = i * 16 + w * 4 + (lane >> 4);
        int chunk = (lane & 15) ^ (row & 7);
        gload_lds16(g + (size_t)row * 128 + chunk * 8, lds + i * 2048 + w * 512);
    }
}

// read a bf16x8 fragment from a swizzled 128x128 tile: logical (row, 16B-chunk)
__device__ __forceinline__ bf16x8 rd_frag(const __bf16* lds, int row, int chunk) {
    return *(const bf16x8*)(lds + row * 128 + ((chunk ^ (row & 7)) * 8));
}

// ---------------------------------------------------------------------------
// cast f32 -> bf16
// ---------------------------------------------------------------------------
__global__ void cast_k(const float* __restrict__ in, __bf16* __restrict__ out, int n4) {
    int i = blockIdx.x * blockDim.x + threadIdx.x;
    if (i < n4) {
        float4 v = ((const float4*)in)[i];
        bf16x4 o;
        o[0] = (__bf16)v.x; o[1] = (__bf16)v.y; o[2] = (__bf16)v.z; o[3] = (__bf16)v.w;
        ((bf16x4*)out)[i] = o;
    }
}

__global__ void wksum_k(const float* __restrict__ Wk, float* __restrict__ wksum) {
    int c = threadIdx.x;
    if (c < D2) {
        float s = 0.0f;
        for (int o = 0; o < D2; ++o) s += Wk[o * D2 + c];
        wksum[c] = s;
    }
}

// kb[n,c] = bf16(wksum[c]*h2[n,c] + bk[c])  -- einsum "oc,bcn->bcn" is a col-scale
__global__ __launch_bounds__(256)
void make_k(const __bf16* __restrict__ h2b, const float* __restrict__ wksum,
            const float* __restrict__ bk, __bf16* __restrict__ kb, int n4) {
    int i = blockIdx.x * blockDim.x + threadIdx.x;
    if (i < n4) {
        bf16x4 h = ((const bf16x4*)h2b)[i];
        int c0 = (i * 4) & (D2 - 1);
        bf16x4 o;
#pragma unroll
        for (int j = 0; j < 4; ++j)
            o[j] = (__bf16)((float)h[j] * wksum[c0 + j] + bk[c0 + j]);
        ((bf16x4*)kb)[i] = o;
    }
}

// ---------------------------------------------------------------------------
// gemm_bt: C[m,n] = sum_k A[m,k]*B[n,k]; 128x128 tile, BK=32, 4 waves.
// AF32: A f32 reg-staged->bf16 LDS. EPI: 1 bias+relu->bf16 ; 3 bias->bf16
// ---------------------------------------------------------------------------
template<bool AF32, int EPI>
__global__ __launch_bounds__(256)
void gemm_bt(const void* __restrict__ Av, const __bf16* __restrict__ B,
             const float* __restrict__ bias, void* __restrict__ Cv,
             int M, int N, int K)
{
    __shared__ __bf16 lA[128 * 32];
    __shared__ __bf16 lB[128 * 32];

    const int t    = threadIdx.x;
    const int lane = t & 63;
    const int w    = t >> 6;
    const int wr   = w >> 1;
    const int wc   = w & 1;
    const int m0   = blockIdx.y * 128;
    const int n0   = blockIdx.x * 128;

    const int rS = w * 16 + (lane >> 2);
    const int cS = (lane & 3) * 8;

    const int fr = lane & 15;
    const int ko = (lane >> 4) * 8;
    const int rj = (lane >> 4) * 4;

    f32x4 acc[4][4] = {};

    for (int k0 = 0; k0 < K; k0 += 32) {
        if constexpr (AF32) {
            const float* Af = (const float*)Av;
            float4 regs[4];
#pragma unroll
            for (int i = 0; i < 4; ++i) {
                int r = i * 32 + (t >> 3);
                regs[i] = *(const float4*)&Af[(size_t)(m0 + r) * K + k0 + (t & 7) * 4];
            }
            __syncthreads();
#pragma unroll
            for (int i = 0; i < 4; ++i) {
                int r = i * 32 + (t >> 3);
                bf16x4 o;
                o[0] = (__bf16)regs[i].x; o[1] = (__bf16)regs[i].y;
                o[2] = (__bf16)regs[i].z; o[3] = (__bf16)regs[i].w;
                *(bf16x4*)&lA[r * 32 + (t & 7) * 4] = o;
            }
            gload_lds16(B + (size_t)(n0 + rS) * K + k0 + cS, lB + w * 512);
            gload_lds16(B + (size_t)(n0 + 64 + rS) * K + k0 + cS, lB + 2048 + w * 512);
            __syncthreads();
        } else {
            const __bf16* Ab = (const __bf16*)Av;
            __syncthreads();
            gload_lds16(Ab + (size_t)(m0 + rS) * K + k0 + cS, lA + w * 512);
            gload_lds16(Ab + (size_t)(m0 + 64 + rS) * K + k0 + cS, lA + 2048 + w * 512);
            gload_lds16(B + (size_t)(n0 + rS) * K + k0 + cS, lB + w * 512);
            gload_lds16(B + (size_t)(n0 + 64 + rS) * K + k0 + cS, lB + 2048 + w * 512);
            __syncthreads();
        }

        bf16x8 af[4], bfr[4];
#pragma unroll
        for (int m = 0; m < 4; ++m)
            af[m] = *(const bf16x8*)&lA[(wr * 64 + m * 16 + fr) * 32 + ko];
#pragma unroll
        for (int n = 0; n < 4; ++n)
            bfr[n] = *(const bf16x8*)&lB[(wc * 64 + n * 16 + fr) * 32 + ko];
#pragma unroll
        for (int m = 0; m < 4; ++m)
#pragma unroll
            for (int n = 0; n < 4; ++n)
                acc[m][n] = __builtin_amdgcn_mfma_f32_16x16x32_bf16(af[m], bfr[n], acc[m][n], 0, 0, 0);
    }

    __bf16* C = (__bf16*)Cv;
#pragma unroll
    for (int n = 0; n < 4; ++n) {
        int col = n0 + wc * 64 + n * 16 + fr;
        float bv = bias[col];
#pragma unroll
        for (int m = 0; m < 4; ++m) {
            int row = m0 + wr * 64 + m * 16 + rj;
#pragma unroll
            for (int j = 0; j < 4; ++j) {
                float v = acc[m][n][j] + bv;
                if constexpr (EPI == 1) v = fmaxf(v, 0.0f);
                C[(size_t)(row + j) * N + col] = (__bf16)v;
            }
        }
    }
}

// ---------------------------------------------------------------------------
// Fused attention. PASS 1: per-(row, chunk-half) online (max,sumexp) partials,
// one partial slot per (ck, wc) since the two wc-waves cover different column
// halves of the same rows (race fixed: slot = ck*2+wc).
// PASS 2: recompute S, write exp(S-M)*invL to attn, accumulate col sums.
// grid (NKC, NQB), 256 threads. Q frags pinned in registers; K double-buffered.
// ---------------------------------------------------------------------------
template<int PASS>
__global__ __launch_bounds__(256)
void fa_kernel(const __bf16* __restrict__ qbuf, const __bf16* __restrict__ kbuf,
               float* __restrict__ pm, float* __restrict__ pl,
               const float* __restrict__ rowM, const float* __restrict__ rowInv,
               float* __restrict__ attn, float* __restrict__ colw)
{
    __shared__ __bf16 Kl[2][KTILE * 128];

    const int t    = threadIdx.x;
    const int lane = t & 63;
    const int w    = t >> 6;
    const int wr   = w >> 1;
    const int wc   = w & 1;
    const int fr   = lane & 15;
    const int hi   = lane >> 4;
    const int ck   = blockIdx.x;
    const int q0   = blockIdx.y * QBLK;
    const int kr0  = ck * KCHUNK;

    // stage Q tile -> LDS -> registers (held for whole kernel)
    stage_tile(qbuf + (size_t)q0 * D2, Kl[0], w, lane);
    __syncthreads();
    bf16x8 af[4][4];
#pragma unroll
    for (int m = 0; m < 4; ++m)
#pragma unroll
        for (int kk = 0; kk < 4; ++kk)
            af[m][kk] = rd_frag(Kl[0], wr * 64 + m * 16 + fr, kk * 4 + hi);
    __syncthreads();

    float mloc[4][4], lloc[4][4], Mr[4][4], Ir[4][4];
#pragma unroll
    for (int m = 0; m < 4; ++m)
#pragma unroll
        for (int j = 0; j < 4; ++j) {
            if constexpr (PASS == 1) { mloc[m][j] = -1e30f; lloc[m][j] = 0.0f; }
            else {
                int r = q0 + wr * 64 + m * 16 + hi * 4 + j;
                Mr[m][j] = rowM[r]; Ir[m][j] = rowInv[r];
            }
        }

    stage_tile(kbuf + (size_t)kr0 * D2, Kl[0], w, lane);
    __syncthreads();

    for (int kt = 0; kt < KCHUNK / KTILE; ++kt) {
        const __bf16* cur = Kl[kt & 1];
        if (kt + 1 < KCHUNK / KTILE)
            stage_tile(kbuf + (size_t)(kr0 + (kt + 1) * KTILE) * D2, Kl[(kt + 1) & 1], w, lane);

        f32x4 acc[4][4] = {};
#pragma unroll
        for (int kk = 0; kk < 4; ++kk) {
            bf16x8 bfr[4];
#pragma unroll
            for (int n = 0; n < 4; ++n)
                bfr[n] = rd_frag(cur, wc * 64 + n * 16 + fr, kk * 4 + hi);
#pragma unroll
            for (int m = 0; m < 4; ++m)
#pragma unroll
                for (int n = 0; n < 4; ++n)
                    acc[m][n] = __builtin_amdgcn_mfma_f32_16x16x32_bf16(af[m][kk], bfr[n], acc[m][n], 0, 0, 0);
        }

        if constexpr (PASS == 1) {
#pragma unroll
            for (int m = 0; m < 4; ++m)
#pragma unroll
                for (int j = 0; j < 4; ++j) {
                    float a0 = acc[m][0][j], a1 = acc[m][1][j], a2 = acc[m][2][j], a3 = acc[m][3][j];
                    float t4 = fmaxf(fmaxf(a0, a1), fmaxf(a2, a3));
                    float mo = mloc[m][j];
                    float mn = fmaxf(mo, t4);
                    float s  = __expf(a0 - mn) + __expf(a1 - mn) + __expf(a2 - mn) + __expf(a3 - mn);
                    lloc[m][j] = lloc[m][j] * __expf(mo - mn) + s;
                    mloc[m][j] = mn;
                }
        } else {
            float csum[4] = {0.0f, 0.0f, 0.0f, 0.0f};
            const int colbase = kr0 + kt * KTILE + wc * 64;
#pragma unroll
            for (int m = 0; m < 4; ++m) {
#pragma unroll
                for (int n = 0; n < 4; ++n) {
                    int col = colbase + n * 16 + fr;
#pragma unroll
                    for (int j = 0; j < 4; ++j) {
                        int row = q0 + wr * 64 + m * 16 + hi * 4 + j;
                        float p = __expf(acc[m][n][j] - Mr[m][j]) * Ir[m][j];
                        attn[(size_t)row * N_TOK + col] = p;
                        csum[n] += p;
                    }
                }
            }
#pragma unroll
            for (int n = 0; n < 4; ++n) {
                csum[n] += __shfl_xor(csum[n], 16);
                csum[n] += __shfl_xor(csum[n], 32);
            }
            if (lane < 16) {
#pragma unroll
                for (int n = 0; n < 4; ++n)
                    atomicAdd(&colw[colbase + n * 16 + lane], csum[n]);
            }
        }
        __syncthreads();
    }

    if constexpr (PASS == 1) {
        // partial slot per (chunk, column-half): slot = ck*2 + wc
        const size_t slot = (size_t)(ck * 2 + wc) * N_TOK;
#pragma unroll
        for (int m = 0; m < 4; ++m)
#pragma unroll
            for (int j = 0; j < 4; ++j) {
                float M = mloc[m][j];
#pragma unroll
                for (int off = 1; off <= 8; off <<= 1) M = fmaxf(M, __shfl_xor(M, off));
                float l = lloc[m][j] * __expf(mloc[m][j] - M);
#pragma unroll
                for (int off = 1; off <= 8; off <<= 1) l += __shfl_xor(l, off);
                if ((lane & 15) == 0) {
                    int r = q0 + wr * 64 + m * 16 + hi * 4 + j;
                    pm[slot + r] = M;
                    pl[slot + r] = l;
                }
            }
    }
}

// combine chunk-half partials (2*NKC slots) -> rowM, rowInv
__global__ __launch_bounds__(256)
void combine_ml(const float* __restrict__ pm, const float* __restrict__ pl,
                float* __restrict__ rowM, float* __restrict__ rowInv) {
    int r = blockIdx.x * 256 + threadIdx.x;
    float M = -1e30f;
#pragma unroll
    for (int c = 0; c < 2 * NKC; ++c) M = fmaxf(M, pm[(size_t)c * N_TOK + r]);
    float L = 0.0f;
#pragma unroll
    for (int c = 0; c < 2 * NKC; ++c)
        L += pl[(size_t)c * N_TOK + r] * __expf(pm[(size_t)c * N_TOK + r] - M);
    rowM[r] = M;
    rowInv[r] = 1.0f / L;
}

// xw[c] = sum_m colw[m]*h2[m,c] ; xh[c] = sum_m h2[m,c]
__global__ __launch_bounds__(256)
void reduce_x2(const __bf16* __restrict__ h2b, const float* __restrict__ colw,
               float* __restrict__ xw, float* __restrict__ xh) {
    int b = blockIdx.x, t = threadIdx.x;
    int c = t & 127, half = t >> 7;
    float aw = 0.0f, ah = 0.0f;
    for (int m = b * 128 + half; m < (b + 1) * 128; m += 2) {
        float h  = (float)h2b[(size_t)m * D2 + c];
        float wv = colw[m];
        aw += wv * h;
        ah += h;
    }
    atomicAdd(&xw[c], aw);
    atomicAdd(&xh[c], ah);
}

__global__ void logits_k(const float* __restrict__ xw, const float* __restrict__ xh,
                         const float* __restrict__ gamma, const float* __restrict__ W3,
                         const float* __restrict__ b3, float* __restrict__ out) {
    __shared__ float x2[D2];
    int t = threadIdx.x;
    float g = gamma[0];
    if (t < D2) x2[t] = (g * xw[t] + xh[t]) * (1.0f / (float)N_TOK);
    __syncthreads();
    if (t < 10) {
        float s = b3[t];
        for (int c = 0; c < D2; ++c) s += x2[c] * W3[t * D2 + c];
        out[t] = s;
    }
}

__global__ void zero_acc(float* __restrict__ colw, float* __restrict__ xw,
                         float* __restrict__ xh) {
    int t = blockIdx.x * 256 + threadIdx.x;
    if (t < N_TOK) colw[t] = 0.0f;
    if (t < D2) { xw[t] = 0.0f; xh[t] = 0.0f; }
}

// ---------------------------------------------------------------------------
extern "C" void kernel_launch(void* const* d_in, const int* in_sizes, int n_in,
                              void* d_out, int out_size, void* d_ws, size_t ws_size,
                              hipStream_t stream) {
    const float* x     = (const float*)d_in[0];
    const float* W1    = (const float*)d_in[1];
    const float* b1    = (const float*)d_in[2];
    const float* W2    = (const float*)d_in[3];
    const float* b2    = (const float*)d_in[4];
    const float* Wq    = (const float*)d_in[5];
    const float* bq    = (const float*)d_in[6];
    const float* Wk    = (const float*)d_in[7];
    const float* bk    = (const float*)d_in[8];
    const float* gamma = (const float*)d_in[9];
    const float* W3    = (const float*)d_in[10];
    const float* b3    = (const float*)d_in[11];

    float* out  = (float*)d_out;
    float* attn = out + 10;            // 8192x8192 f32

    char* p = (char*)d_ws;
    __bf16* w1b = (__bf16*)p; p += (size_t)D1 * IN_FEAT * 2;
    __bf16* w2b = (__bf16*)p; p += (size_t)D2 * D1 * 2;
    __bf16* wqb = (__bf16*)p; p += (size_t)D2 * D2 * 2;
    __bf16* h1b = (__bf16*)p; p += (size_t)N_TOK * D1 * 2;
    __bf16* h2b = (__bf16*)p; p += (size_t)N_TOK * D2 * 2;
    __bf16* qb  = (__bf16*)p; p += (size_t)N_TOK * D2 * 2;
    __bf16* kb  = (__bf16*)p; p += (size_t)N_TOK * D2 * 2;
    float* pm     = (float*)p; p += (size_t)2 * NKC * N_TOK * 4;
    float* pl     = (float*)p; p += (size_t)2 * NKC * N_TOK * 4;
    float* rowM   = (float*)p; p += N_TOK * 4;
    float* rowInv = (float*)p; p += N_TOK * 4;
    float* colw   = (float*)p; p += N_TOK * 4;
    float* wksum  = (float*)p; p += D2 * 4;
    float* xw     = (float*)p; p += D2 * 4;
    float* xh     = (float*)p; p += D2 * 4;

    zero_acc<<<32, 256, 0, stream>>>(colw, xw, xh);
    cast_k<<<1024, 256, 0, stream>>>(W1, w1b, D1 * IN_FEAT / 4);
    cast_k<<<64,   256, 0, stream>>>(W2, w2b, D2 * D1 / 4);
    cast_k<<<16,   256, 0, stream>>>(Wq, wqb, D2 * D2 / 4);
    wksum_k<<<1, 128, 0, stream>>>(Wk, wksum);

    gemm_bt<true, 1><<<dim3(D1 / 128, N_TOK / 128), 256, 0, stream>>>(
        x, w1b, b1, h1b, N_TOK, D1, IN_FEAT);
    gemm_bt<false, 1><<<dim3(D2 / 128, N_TOK / 128), 256, 0, stream>>>(
        h1b, w2b, b2, h2b, N_TOK, D2, D1);
    gemm_bt<false, 3><<<dim3(D2 / 128, N_TOK / 128), 256, 0, stream>>>(
        h2b, wqb, bq, qb, N_TOK, D2, D2);
    make_k<<<1024, 256, 0, stream>>>(h2b, wksum, bk, kb, N_TOK * D2 / 4);

    fa_kernel<1><<<dim3(NKC, NQB), 256, 0, stream>>>(
        qb, kb, pm, pl, nullptr, nullptr, nullptr, nullptr);
    combine_ml<<<N_TOK / 256, 256, 0, stream>>>(pm, pl, rowM, rowInv);
    fa_kernel<2><<<dim3(NKC, NQB), 256, 0, stream>>>(
        qb, kb, nullptr, nullptr, rowM, rowInv, attn, colw);

    reduce_x2<<<64, 256, 0, stream>>>(h2b, colw, xw, xh);
    logits_k<<<1, 128, 0, stream>>>(xw, xh, gamma, W3, b3, out);
}

// Round 5
// 301.720 us; speedup vs baseline: 1.4147x; 1.0731x over previous
//
#include <hip/hip_runtime.h>
#include <hip/hip_bf16.h>

typedef __attribute__((ext_vector_type(8))) __bf16 bf16x8;
typedef __attribute__((ext_vector_type(4))) __bf16 bf16x4;
typedef __attribute__((ext_vector_type(4))) float f32x4;

#define N_TOK 8192
#define IN_FEAT 2048
#define D1 512
#define D2 128
#define QBLK 128
#define KCHUNK 1024
#define KTILE 128
#define NKC (N_TOK / KCHUNK)   // 8
#define NQB (N_TOK / QBLK)     // 64

__device__ __forceinline__ void gload_lds16(const __bf16* g, __bf16* l) {
    __builtin_amdgcn_global_load_lds(
        (const __attribute__((address_space(1))) void*)g,
        (__attribute__((address_space(3))) void*)l,
        16, 0, 0);
}

// ---------------------------------------------------------------------------
// Stage a 128x128 bf16 tile global->LDS, linear LDS dest, XOR-swizzled SOURCE
// (chunk ^= row&7) so swizzled reads land right (rule 21).
// ---------------------------------------------------------------------------
__device__ __forceinline__ void stage_tile(const __bf16* __restrict__ g,
                                           __bf16* lds, int w, int lane) {
#pragma unroll
    for (int i = 0; i < 8; ++i) {
        int row   = i * 16 + w * 4 + (lane >> 4);
        int chunk = (lane & 15) ^ (row & 7);
        gload_lds16(g + (size_t)row * 128 + chunk * 8, lds + i * 2048 + w * 512);
    }
}

// read a bf16x8 fragment from a swizzled 128x128 tile: logical (row, 16B-chunk)
__device__ __forceinline__ bf16x8 rd_frag(const __bf16* lds, int row, int chunk) {
    return *(const bf16x8*)(lds + row * 128 + ((chunk ^ (row & 7)) * 8));
}

// ---------------------------------------------------------------------------
// prep: fused weight casts + wksum + accumulator zeros (one launch)
// blocks 0-1023: W1 cast; 1024-1087: W2; 1088-1103: Wq; 1104-1135: colw zero;
// 1136: wksum + xw/xh zero
// ---------------------------------------------------------------------------
__global__ __launch_bounds__(256)
void prep(const float* __restrict__ W1, __bf16* __restrict__ w1b,
          const float* __restrict__ W2, __bf16* __restrict__ w2b,
          const float* __restrict__ Wq, __bf16* __restrict__ wqb,
          const float* __restrict__ Wk, float* __restrict__ wksum,
          float* __restrict__ colw, float* __restrict__ xw, float* __restrict__ xh) {
    int b = blockIdx.x, t = threadIdx.x;
    const float* src = nullptr; __bf16* dst = nullptr; int i = 0;
    if (b < 1024)      { src = W1; dst = w1b; i = b * 256 + t; }
    else if (b < 1088) { src = W2; dst = w2b; i = (b - 1024) * 256 + t; }
    else if (b < 1104) { src = Wq; dst = wqb; i = (b - 1088) * 256 + t; }
    else if (b < 1136) { colw[(b - 1104) * 256 + t] = 0.0f; return; }
    else {
        if (t < D2) {
            float s = 0.0f;
            for (int o = 0; o < D2; ++o) s += Wk[o * D2 + t];
            wksum[t] = s;
            xw[t] = 0.0f; xh[t] = 0.0f;
        }
        return;
    }
    float4 v = ((const float4*)src)[i];
    bf16x4 o;
    o[0] = (__bf16)v.x; o[1] = (__bf16)v.y; o[2] = (__bf16)v.z; o[3] = (__bf16)v.w;
    ((bf16x4*)dst)[i] = o;
}

// ---------------------------------------------------------------------------
// gemm1: h1 = relu(x @ W1^T + b1). A f32 reg-staged. BM=128 BN=64 BK=32.
// grid (512/64=8, 8192/128=64) = 512 blocks -> 2 blocks/CU.
// ---------------------------------------------------------------------------
__global__ __launch_bounds__(256)
void gemm1_k(const float* __restrict__ x, const __bf16* __restrict__ w1b,
             const float* __restrict__ b1, __bf16* __restrict__ h1b) {
    __shared__ __bf16 lA[128 * 32];
    __shared__ __bf16 lB[64 * 32];

    const int t    = threadIdx.x;
    const int lane = t & 63;
    const int w    = t >> 6;
    const int wr   = w >> 1;
    const int wc   = w & 1;
    const int m0   = blockIdx.y * 128;
    const int n0   = blockIdx.x * 64;

    const int rS = w * 16 + (lane >> 2);
    const int cS = (lane & 3) * 8;
    const int fr = lane & 15;
    const int hi = lane >> 4;
    const int ko = hi * 8;
    const int rj = hi * 4;

    f32x4 acc[4][2] = {};

    for (int k0 = 0; k0 < IN_FEAT; k0 += 32) {
        float4 regs[4];
#pragma unroll
        for (int i = 0; i < 4; ++i) {
            int r = i * 32 + (t >> 3);
            regs[i] = *(const float4*)&x[(size_t)(m0 + r) * IN_FEAT + k0 + (t & 7) * 4];
        }
        __syncthreads();
#pragma unroll
        for (int i = 0; i < 4; ++i) {
            int r = i * 32 + (t >> 3);
            bf16x4 o;
            o[0] = (__bf16)regs[i].x; o[1] = (__bf16)regs[i].y;
            o[2] = (__bf16)regs[i].z; o[3] = (__bf16)regs[i].w;
            *(bf16x4*)&lA[r * 32 + (t & 7) * 4] = o;
        }
        gload_lds16(w1b + (size_t)(n0 + rS) * IN_FEAT + k0 + cS, lB + w * 512);
        __syncthreads();

        bf16x8 af[4], bf[2];
#pragma unroll
        for (int m = 0; m < 4; ++m)
            af[m] = *(const bf16x8*)&lA[(wr * 64 + m * 16 + fr) * 32 + ko];
#pragma unroll
        for (int n = 0; n < 2; ++n)
            bf[n] = *(const bf16x8*)&lB[(wc * 32 + n * 16 + fr) * 32 + ko];
#pragma unroll
        for (int m = 0; m < 4; ++m)
#pragma unroll
            for (int n = 0; n < 2; ++n)
                acc[m][n] = __builtin_amdgcn_mfma_f32_16x16x32_bf16(af[m], bf[n], acc[m][n], 0, 0, 0);
    }

#pragma unroll
    for (int n = 0; n < 2; ++n) {
        int col = n0 + wc * 32 + n * 16 + fr;
        float bv = b1[col];
#pragma unroll
        for (int m = 0; m < 4; ++m) {
            int row = m0 + wr * 64 + m * 16 + rj;
#pragma unroll
            for (int j = 0; j < 4; ++j)
                h1b[(size_t)(row + j) * D1 + col] = (__bf16)fmaxf(acc[m][n][j] + bv, 0.0f);
        }
    }
}

// ---------------------------------------------------------------------------
// mlp2: per 32-row block: h2 = relu(h1 @ W2^T + b2) -> h2b, kb (col-scale),
// keep h2 tile in swizzled LDS, then q = h2 @ Wq^T + bq -> qb.
// grid 256 blocks, 4 waves; wave w owns cols [w*32, w*32+32).
// ---------------------------------------------------------------------------
__global__ __launch_bounds__(256)
void mlp2_k(const __bf16* __restrict__ h1b, const __bf16* __restrict__ w2b,
            const float* __restrict__ b2, const __bf16* __restrict__ wqb,
            const float* __restrict__ bq, const float* __restrict__ wksum,
            const float* __restrict__ bk, __bf16* __restrict__ h2b,
            __bf16* __restrict__ kb, __bf16* __restrict__ qb) {
    __shared__ __bf16 lA[32 * 32];    // 2 KB
    __shared__ __bf16 lB[128 * 32];   // 8 KB
    __shared__ __bf16 lH[32 * 128];   // 8 KB (chunk-swizzled)

    const int t    = threadIdx.x;
    const int lane = t & 63;
    const int w    = t >> 6;
    const int fr   = lane & 15;
    const int hi   = lane >> 4;
    const int ko   = hi * 8;
    const int m0   = blockIdx.x * 32;

    f32x4 acc[2][2] = {};

    for (int k0 = 0; k0 < D1; k0 += 32) {
        __syncthreads();
        if (w < 2)
            gload_lds16(h1b + (size_t)(m0 + w * 16 + (lane >> 2)) * D1 + k0 + (lane & 3) * 8,
                        lA + w * 512);
#pragma unroll
        for (int i = 0; i < 2; ++i) {
            int row = w * 32 + i * 16 + (lane >> 2);
            gload_lds16(w2b + (size_t)row * D1 + k0 + (lane & 3) * 8,
                        lB + w * 1024 + i * 512);
        }
        __syncthreads();

        bf16x8 af[2], bf[2];
#pragma unroll
        for (int m = 0; m < 2; ++m)
            af[m] = *(const bf16x8*)&lA[(m * 16 + fr) * 32 + ko];
#pragma unroll
        for (int n = 0; n < 2; ++n)
            bf[n] = *(const bf16x8*)&lB[(w * 32 + n * 16 + fr) * 32 + ko];
#pragma unroll
        for (int m = 0; m < 2; ++m)
#pragma unroll
            for (int n = 0; n < 2; ++n)
                acc[m][n] = __builtin_amdgcn_mfma_f32_16x16x32_bf16(af[m], bf[n], acc[m][n], 0, 0, 0);
    }

    // epilogue A: h2b, kb, and swizzled LDS copy for phase B
#pragma unroll
    for (int n = 0; n < 2; ++n) {
        int col = w * 32 + n * 16 + fr;
        float bv = b2[col], wv = wksum[col], bkv = bk[col];
#pragma unroll
        for (int m = 0; m < 2; ++m) {
#pragma unroll
            for (int j = 0; j < 4; ++j) {
                int row = m * 16 + hi * 4 + j;     // local 0..31
                float v = fmaxf(acc[m][n][j] + bv, 0.0f);
                h2b[(size_t)(m0 + row) * D2 + col] = (__bf16)v;
                kb [(size_t)(m0 + row) * D2 + col] = (__bf16)(wv * v + bkv);
                lH[row * 128 + (((col >> 3) ^ (row & 7)) * 8) + (col & 7)] = (__bf16)v;
            }
        }
    }
    __syncthreads();

    // phase B: q = lH . Wq^T (K=128); Wq frags read straight from global (L2)
    f32x4 acc2[2][2] = {};
#pragma unroll
    for (int kk = 0; kk < 4; ++kk) {
        bf16x8 af2[2], bf2[2];
#pragma unroll
        for (int m = 0; m < 2; ++m) {
            int row = m * 16 + fr;
            af2[m] = *(const bf16x8*)&lH[row * 128 + (((kk * 4 + hi) ^ (row & 7)) * 8)];
        }
#pragma unroll
        for (int n = 0; n < 2; ++n)
            bf2[n] = *(const bf16x8*)&wqb[(size_t)(w * 32 + n * 16 + fr) * D2 + kk * 32 + ko];
#pragma unroll
        for (int m = 0; m < 2; ++m)
#pragma unroll
            for (int n = 0; n < 2; ++n)
                acc2[m][n] = __builtin_amdgcn_mfma_f32_16x16x32_bf16(af2[m], bf2[n], acc2[m][n], 0, 0, 0);
    }
#pragma unroll
    for (int n = 0; n < 2; ++n) {
        int col = w * 32 + n * 16 + fr;
        float bv = bq[col];
#pragma unroll
        for (int m = 0; m < 2; ++m)
#pragma unroll
            for (int j = 0; j < 4; ++j) {
                int row = m0 + m * 16 + hi * 4 + j;
                qb[(size_t)row * D2 + col] = (__bf16)(acc2[m][n][j] + bv);
            }
    }
}

// ---------------------------------------------------------------------------
// Fused attention. PASS 1: per-(row, chunk-half) online (max,sumexp) partials,
// slot = ck*2+wc (the two wc-waves cover different column halves of a row).
// PASS 2: recompute S, write exp(S-M)*invL to attn, accumulate col sums.
// ---------------------------------------------------------------------------
template<int PASS>
__global__ __launch_bounds__(256, 2)
void fa_kernel(const __bf16* __restrict__ qbuf, const __bf16* __restrict__ kbuf,
               float* __restrict__ pm, float* __restrict__ pl,
               const float* __restrict__ rowM, const float* __restrict__ rowInv,
               float* __restrict__ attn, float* __restrict__ colw)
{
    __shared__ __bf16 Kl[2][KTILE * 128];

    const int t    = threadIdx.x;
    const int lane = t & 63;
    const int w    = t >> 6;
    const int wr   = w >> 1;
    const int wc   = w & 1;
    const int fr   = lane & 15;
    const int hi   = lane >> 4;
    const int ck   = blockIdx.x;
    const int q0   = blockIdx.y * QBLK;
    const int kr0  = ck * KCHUNK;

    stage_tile(qbuf + (size_t)q0 * D2, Kl[0], w, lane);
    __syncthreads();
    bf16x8 af[4][4];
#pragma unroll
    for (int m = 0; m < 4; ++m)
#pragma unroll
        for (int kk = 0; kk < 4; ++kk)
            af[m][kk] = rd_frag(Kl[0], wr * 64 + m * 16 + fr, kk * 4 + hi);
    __syncthreads();

    float mloc[4][4], lloc[4][4], Mr[4][4], Ir[4][4];
#pragma unroll
    for (int m = 0; m < 4; ++m)
#pragma unroll
        for (int j = 0; j < 4; ++j) {
            if constexpr (PASS == 1) { mloc[m][j] = -1e30f; lloc[m][j] = 0.0f; }
            else {
                int r = q0 + wr * 64 + m * 16 + hi * 4 + j;
                Mr[m][j] = rowM[r]; Ir[m][j] = rowInv[r];
            }
        }

    stage_tile(kbuf + (size_t)kr0 * D2, Kl[0], w, lane);
    __syncthreads();

    for (int kt = 0; kt < KCHUNK / KTILE; ++kt) {
        const __bf16* cur = Kl[kt & 1];
        if (kt + 1 < KCHUNK / KTILE)
            stage_tile(kbuf + (size_t)(kr0 + (kt + 1) * KTILE) * D2, Kl[(kt + 1) & 1], w, lane);

        f32x4 acc[4][4] = {};
#pragma unroll
        for (int kk = 0; kk < 4; ++kk) {
            bf16x8 bfr[4];
#pragma unroll
            for (int n = 0; n < 4; ++n)
                bfr[n] = rd_frag(cur, wc * 64 + n * 16 + fr, kk * 4 + hi);
#pragma unroll
            for (int m = 0; m < 4; ++m)
#pragma unroll
                for (int n = 0; n < 4; ++n)
                    acc[m][n] = __builtin_amdgcn_mfma_f32_16x16x32_bf16(af[m][kk], bfr[n], acc[m][n], 0, 0, 0);
        }

        if constexpr (PASS == 1) {
#pragma unroll
            for (int m = 0; m < 4; ++m)
#pragma unroll
                for (int j = 0; j < 4; ++j) {
                    float a0 = acc[m][0][j], a1 = acc[m][1][j], a2 = acc[m][2][j], a3 = acc[m][3][j];
                    float t4 = fmaxf(fmaxf(a0, a1), fmaxf(a2, a3));
                    float mo = mloc[m][j];
                    float mn = fmaxf(mo, t4);
                    float s  = __expf(a0 - mn) + __expf(a1 - mn) + __expf(a2 - mn) + __expf(a3 - mn);
                    lloc[m][j] = lloc[m][j] * __expf(mo - mn) + s;
                    mloc[m][j] = mn;
                }
        } else {
            float csum[4] = {0.0f, 0.0f, 0.0f, 0.0f};
            const int colbase = kr0 + kt * KTILE + wc * 64;
#pragma unroll
            for (int m = 0; m < 4; ++m) {
#pragma unroll
                for (int n = 0; n < 4; ++n) {
                    int col = colbase + n * 16 + fr;
#pragma unroll
                    for (int j = 0; j < 4; ++j) {
                        int row = q0 + wr * 64 + m * 16 + hi * 4 + j;
                        float p = __expf(acc[m][n][j] - Mr[m][j]) * Ir[m][j];
                        attn[(size_t)row * N_TOK + col] = p;
                        csum[n] += p;
                    }
                }
            }
#pragma unroll
            for (int n = 0; n < 4; ++n) {
                csum[n] += __shfl_xor(csum[n], 16);
                csum[n] += __shfl_xor(csum[n], 32);
            }
            if (lane < 16) {
#pragma unroll
                for (int n = 0; n < 4; ++n)
                    atomicAdd(&colw[colbase + n * 16 + lane], csum[n]);
            }
        }
        __syncthreads();
    }

    if constexpr (PASS == 1) {
        const size_t slot = (size_t)(ck * 2 + wc) * N_TOK;
#pragma unroll
        for (int m = 0; m < 4; ++m)
#pragma unroll
            for (int j = 0; j < 4; ++j) {
                float M = mloc[m][j];
#pragma unroll
                for (int off = 1; off <= 8; off <<= 1) M = fmaxf(M, __shfl_xor(M, off));
                float l = lloc[m][j] * __expf(mloc[m][j] - M);
#pragma unroll
                for (int off = 1; off <= 8; off <<= 1) l += __shfl_xor(l, off);
                if ((lane & 15) == 0) {
                    int r = q0 + wr * 64 + m * 16 + hi * 4 + j;
                    pm[slot + r] = M;
                    pl[slot + r] = l;
                }
            }
    }
}

// combine chunk-half partials (2*NKC slots) -> rowM, rowInv
__global__ __launch_bounds__(256)
void combine_ml(const float* __restrict__ pm, const float* __restrict__ pl,
                float* __restrict__ rowM, float* __restrict__ rowInv) {
    int r = blockIdx.x * 256 + threadIdx.x;
    float M = -1e30f;
#pragma unroll
    for (int c = 0; c < 2 * NKC; ++c) M = fmaxf(M, pm[(size_t)c * N_TOK + r]);
    float L = 0.0f;
#pragma unroll
    for (int c = 0; c < 2 * NKC; ++c)
        L += pl[(size_t)c * N_TOK + r] * __expf(pm[(size_t)c * N_TOK + r] - M);
    rowM[r] = M;
    rowInv[r] = 1.0f / L;
}

// xw[c] = sum_m colw[m]*h2[m,c] ; xh[c] = sum_m h2[m,c]
__global__ __launch_bounds__(256)
void reduce_x2(const __bf16* __restrict__ h2b, const float* __restrict__ colw,
               float* __restrict__ xw, float* __restrict__ xh) {
    int b = blockIdx.x, t = threadIdx.x;
    int c = t & 127, half = t >> 7;
    float aw = 0.0f, ah = 0.0f;
    for (int m = b * 128 + half; m < (b + 1) * 128; m += 2) {
        float h  = (float)h2b[(size_t)m * D2 + c];
        float wv = colw[m];
        aw += wv * h;
        ah += h;
    }
    atomicAdd(&xw[c], aw);
    atomicAdd(&xh[c], ah);
}

__global__ void logits_k(const float* __restrict__ xw, const float* __restrict__ xh,
                         const float* __restrict__ gamma, const float* __restrict__ W3,
                         const float* __restrict__ b3, float* __restrict__ out) {
    __shared__ float x2[D2];
    int t = threadIdx.x;
    float g = gamma[0];
    if (t < D2) x2[t] = (g * xw[t] + xh[t]) * (1.0f / (float)N_TOK);
    __syncthreads();
    if (t < 10) {
        float s = b3[t];
        for (int c = 0; c < D2; ++c) s += x2[c] * W3[t * D2 + c];
        out[t] = s;
    }
}

// ---------------------------------------------------------------------------
extern "C" void kernel_launch(void* const* d_in, const int* in_sizes, int n_in,
                              void* d_out, int out_size, void* d_ws, size_t ws_size,
                              hipStream_t stream) {
    const float* x     = (const float*)d_in[0];
    const float* W1    = (const float*)d_in[1];
    const float* b1    = (const float*)d_in[2];
    const float* W2    = (const float*)d_in[3];
    const float* b2    = (const float*)d_in[4];
    const float* Wq    = (const float*)d_in[5];
    const float* bq    = (const float*)d_in[6];
    const float* Wk    = (const float*)d_in[7];
    const float* bk    = (const float*)d_in[8];
    const float* gamma = (const float*)d_in[9];
    const float* W3    = (const float*)d_in[10];
    const float* b3    = (const float*)d_in[11];

    float* out  = (float*)d_out;
    float* attn = out + 10;            // 8192x8192 f32

    char* p = (char*)d_ws;
    __bf16* w1b = (__bf16*)p; p += (size_t)D1 * IN_FEAT * 2;
    __bf16* w2b = (__bf16*)p; p += (size_t)D2 * D1 * 2;
    __bf16* wqb = (__bf16*)p; p += (size_t)D2 * D2 * 2;
    __bf16* h1b = (__bf16*)p; p += (size_t)N_TOK * D1 * 2;
    __bf16* h2b = (__bf16*)p; p += (size_t)N_TOK * D2 * 2;
    __bf16* qb  = (__bf16*)p; p += (size_t)N_TOK * D2 * 2;
    __bf16* kb  = (__bf16*)p; p += (size_t)N_TOK * D2 * 2;
    float* pm     = (float*)p; p += (size_t)2 * NKC * N_TOK * 4;
    float* pl     = (float*)p; p += (size_t)2 * NKC * N_TOK * 4;
    float* rowM   = (float*)p; p += N_TOK * 4;
    float* rowInv = (float*)p; p += N_TOK * 4;
    float* colw   = (float*)p; p += N_TOK * 4;
    float* wksum  = (float*)p; p += D2 * 4;
    float* xw     = (float*)p; p += D2 * 4;
    float* xh     = (float*)p; p += D2 * 4;

    prep<<<1137, 256, 0, stream>>>(W1, w1b, W2, w2b, Wq, wqb, Wk, wksum, colw, xw, xh);

    gemm1_k<<<dim3(D1 / 64, N_TOK / 128), 256, 0, stream>>>(x, w1b, b1, h1b);
    mlp2_k<<<N_TOK / 32, 256, 0, stream>>>(h1b, w2b, b2, wqb, bq, wksum, bk, h2b, kb, qb);

    fa_kernel<1><<<dim3(NKC, NQB), 256, 0, stream>>>(
        qb, kb, pm, pl, nullptr, nullptr, nullptr, nullptr);
    combine_ml<<<N_TOK / 256, 256, 0, stream>>>(pm, pl, rowM, rowInv);
    fa_kernel<2><<<dim3(NKC, NQB), 256, 0, stream>>>(
        qb, kb, nullptr, nullptr, rowM, rowInv, attn, colw);

    reduce_x2<<<64, 256, 0, stream>>>(h2b, colw, xw, xh);
    logits_k<<<1, 128, 0, stream>>>(xw, xh, gamma, W3, b3, out);
}

// Round 6
// 292.501 us; speedup vs baseline: 1.4593x; 1.0315x over previous
//
#include <hip/hip_runtime.h>
#include <hip/hip_bf16.h>

typedef __attribute__((ext_vector_type(8))) __bf16 bf16x8;
typedef __attribute__((ext_vector_type(4))) __bf16 bf16x4;
typedef __attribute__((ext_vector_type(4))) float f32x4;

#define N_TOK 8192
#define IN_FEAT 2048
#define D1 512
#define D2 128
#define QBLK 128
#define KCHUNK 1024
#define KTILE 128
#define NKC (N_TOK / KCHUNK)   // 8
#define NQB (N_TOK / QBLK)     // 64

__device__ __forceinline__ void gload_lds16(const __bf16* g, __bf16* l) {
    __builtin_amdgcn_global_load_lds(
        (const __attribute__((address_space(1))) void*)g,
        (__attribute__((address_space(3))) void*)l,
        16, 0, 0);
}

// ---------------------------------------------------------------------------
// Stage a 128x128 bf16 tile global->LDS, linear LDS dest, XOR-swizzled SOURCE
// (chunk ^= row&7) so swizzled reads land right (rule 21).
// ---------------------------------------------------------------------------
__device__ __forceinline__ void stage_tile(const __bf16* __restrict__ g,
                                           __bf16* lds, int w, int lane) {
#pragma unroll
    for (int i = 0; i < 8; ++i) {
        int row   = i * 16 + w * 4 + (lane >> 4);
        int chunk = (lane & 15) ^ (row & 7);
        gload_lds16(g + (size_t)row * 128 + chunk * 8, lds + i * 2048 + w * 512);
    }
}

// read a bf16x8 fragment from a swizzled 128x128 tile: logical (row, 16B-chunk)
__device__ __forceinline__ bf16x8 rd_frag(const __bf16* lds, int row, int chunk) {
    return *(const bf16x8*)(lds + row * 128 + ((chunk ^ (row & 7)) * 8));
}

// ---------------------------------------------------------------------------
// prep: fused weight casts + wksum + accumulator zeros (one launch)
// ---------------------------------------------------------------------------
__global__ __launch_bounds__(256)
void prep(const float* __restrict__ W1, __bf16* __restrict__ w1b,
          const float* __restrict__ W2, __bf16* __restrict__ w2b,
          const float* __restrict__ Wq, __bf16* __restrict__ wqb,
          const float* __restrict__ Wk, float* __restrict__ wksum,
          float* __restrict__ colw, float* __restrict__ xw, float* __restrict__ xh) {
    int b = blockIdx.x, t = threadIdx.x;
    const float* src = nullptr; __bf16* dst = nullptr; int i = 0;
    if (b < 1024)      { src = W1; dst = w1b; i = b * 256 + t; }
    else if (b < 1088) { src = W2; dst = w2b; i = (b - 1024) * 256 + t; }
    else if (b < 1104) { src = Wq; dst = wqb; i = (b - 1088) * 256 + t; }
    else if (b < 1136) { colw[(b - 1104) * 256 + t] = 0.0f; return; }
    else {
        if (t < D2) {
            float s = 0.0f;
            for (int o = 0; o < D2; ++o) s += Wk[o * D2 + t];
            wksum[t] = s;
            xw[t] = 0.0f; xh[t] = 0.0f;
        }
        return;
    }
    float4 v = ((const float4*)src)[i];
    bf16x4 o;
    o[0] = (__bf16)v.x; o[1] = (__bf16)v.y; o[2] = (__bf16)v.z; o[3] = (__bf16)v.w;
    ((bf16x4*)dst)[i] = o;
}

// ---------------------------------------------------------------------------
// gemm1: h1 = relu(x @ W1^T + b1). A f32 reg-staged + prefetch. BM=128 BN=64.
// 1D grid 512; decode y=b&63, x=b>>6 so the 8 n-blocks sharing an x-strip
// have b%8==y%8 -> SAME XCD -> x-strip streams through one L2 (T1).
// ---------------------------------------------------------------------------
__global__ __launch_bounds__(256)
void gemm1_k(const float* __restrict__ x, const __bf16* __restrict__ w1b,
             const float* __restrict__ b1, __bf16* __restrict__ h1b) {
    __shared__ __bf16 lA[128 * 32];
    __shared__ __bf16 lB[64 * 32];

    const int t    = threadIdx.x;
    const int lane = t & 63;
    const int w    = t >> 6;
    const int wr   = w >> 1;
    const int wc   = w & 1;
    const int b    = blockIdx.x;
    const int m0   = (b & 63) * 128;
    const int n0   = (b >> 6) * 64;

    const int rS = w * 16 + (lane >> 2);
    const int cS = (lane & 3) * 8;
    const int fr = lane & 15;
    const int hi = lane >> 4;
    const int ko = hi * 8;
    const int rj = hi * 4;

    const int ar = t >> 3;            // A staging row 0..31 (+i*32)
    const int ac = (t & 7) * 4;       // A staging col

    f32x4 acc[4][2] = {};

    float4 regs[4];
#pragma unroll
    for (int i = 0; i < 4; ++i)
        regs[i] = *(const float4*)&x[(size_t)(m0 + i * 32 + ar) * IN_FEAT + ac];

    for (int k0 = 0; k0 < IN_FEAT; k0 += 32) {
        __syncthreads();   // previous tile consumed
#pragma unroll
        for (int i = 0; i < 4; ++i) {
            bf16x4 o;
            o[0] = (__bf16)regs[i].x; o[1] = (__bf16)regs[i].y;
            o[2] = (__bf16)regs[i].z; o[3] = (__bf16)regs[i].w;
            *(bf16x4*)&lA[(i * 32 + ar) * 32 + ac] = o;
        }
        gload_lds16(w1b + (size_t)(n0 + rS) * IN_FEAT + k0 + cS, lB + w * 512);
        __syncthreads();   // tiles ready (drains vmcnt+lgkmcnt)

        if (k0 + 32 < IN_FEAT) {       // prefetch next A tile; latency hides under MFMA
#pragma unroll
            for (int i = 0; i < 4; ++i)
                regs[i] = *(const float4*)&x[(size_t)(m0 + i * 32 + ar) * IN_FEAT + k0 + 32 + ac];
        }

        bf16x8 af[4], bf[2];
#pragma unroll
        for (int m = 0; m < 4; ++m)
            af[m] = *(const bf16x8*)&lA[(wr * 64 + m * 16 + fr) * 32 + ko];
#pragma unroll
        for (int n = 0; n < 2; ++n)
            bf[n] = *(const bf16x8*)&lB[(wc * 32 + n * 16 + fr) * 32 + ko];
#pragma unroll
        for (int m = 0; m < 4; ++m)
#pragma unroll
            for (int n = 0; n < 2; ++n)
                acc[m][n] = __builtin_amdgcn_mfma_f32_16x16x32_bf16(af[m], bf[n], acc[m][n], 0, 0, 0);
    }

#pragma unroll
    for (int n = 0; n < 2; ++n) {
        int col = n0 + wc * 32 + n * 16 + fr;
        float bv = b1[col];
#pragma unroll
        for (int m = 0; m < 4; ++m) {
            int row = m0 + wr * 64 + m * 16 + rj;
#pragma unroll
            for (int j = 0; j < 4; ++j)
                h1b[(size_t)(row + j) * D1 + col] = (__bf16)fmaxf(acc[m][n][j] + bv, 0.0f);
        }
    }
}

// ---------------------------------------------------------------------------
// mlp2: per 32-row block: h2 = relu(h1 @ W2^T + b2) -> h2b, kb (col-scale),
// keep h2 tile in swizzled LDS, then q = h2 @ Wq^T + bq -> qb.
// ---------------------------------------------------------------------------
__global__ __launch_bounds__(256)
void mlp2_k(const __bf16* __restrict__ h1b, const __bf16* __restrict__ w2b,
            const float* __restrict__ b2, const __bf16* __restrict__ wqb,
            const float* __restrict__ bq, const float* __restrict__ wksum,
            const float* __restrict__ bk, __bf16* __restrict__ h2b,
            __bf16* __restrict__ kb, __bf16* __restrict__ qb) {
    __shared__ __bf16 lA[32 * 32];
    __shared__ __bf16 lB[128 * 32];
    __shared__ __bf16 lH[32 * 128];

    const int t    = threadIdx.x;
    const int lane = t & 63;
    const int w    = t >> 6;
    const int fr   = lane & 15;
    const int hi   = lane >> 4;
    const int ko   = hi * 8;
    const int m0   = blockIdx.x * 32;

    f32x4 acc[2][2] = {};

    for (int k0 = 0; k0 < D1; k0 += 32) {
        __syncthreads();
        if (w < 2)
            gload_lds16(h1b + (size_t)(m0 + w * 16 + (lane >> 2)) * D1 + k0 + (lane & 3) * 8,
                        lA + w * 512);
#pragma unroll
        for (int i = 0; i < 2; ++i) {
            int row = w * 32 + i * 16 + (lane >> 2);
            gload_lds16(w2b + (size_t)row * D1 + k0 + (lane & 3) * 8,
                        lB + w * 1024 + i * 512);
        }
        __syncthreads();

        bf16x8 af[2], bf[2];
#pragma unroll
        for (int m = 0; m < 2; ++m)
            af[m] = *(const bf16x8*)&lA[(m * 16 + fr) * 32 + ko];
#pragma unroll
        for (int n = 0; n < 2; ++n)
            bf[n] = *(const bf16x8*)&lB[(w * 32 + n * 16 + fr) * 32 + ko];
#pragma unroll
        for (int m = 0; m < 2; ++m)
#pragma unroll
            for (int n = 0; n < 2; ++n)
                acc[m][n] = __builtin_amdgcn_mfma_f32_16x16x32_bf16(af[m], bf[n], acc[m][n], 0, 0, 0);
    }

#pragma unroll
    for (int n = 0; n < 2; ++n) {
        int col = w * 32 + n * 16 + fr;
        float bv = b2[col], wv = wksum[col], bkv = bk[col];
#pragma unroll
        for (int m = 0; m < 2; ++m) {
#pragma unroll
            for (int j = 0; j < 4; ++j) {
                int row = m * 16 + hi * 4 + j;
                float v = fmaxf(acc[m][n][j] + bv, 0.0f);
                h2b[(size_t)(m0 + row) * D2 + col] = (__bf16)v;
                kb [(size_t)(m0 + row) * D2 + col] = (__bf16)(wv * v + bkv);
                lH[row * 128 + (((col >> 3) ^ (row & 7)) * 8) + (col & 7)] = (__bf16)v;
            }
        }
    }
    __syncthreads();

    f32x4 acc2[2][2] = {};
#pragma unroll
    for (int kk = 0; kk < 4; ++kk) {
        bf16x8 af2[2], bf2[2];
#pragma unroll
        for (int m = 0; m < 2; ++m) {
            int row = m * 16 + fr;
            af2[m] = *(const bf16x8*)&lH[row * 128 + (((kk * 4 + hi) ^ (row & 7)) * 8)];
        }
#pragma unroll
        for (int n = 0; n < 2; ++n)
            bf2[n] = *(const bf16x8*)&wqb[(size_t)(w * 32 + n * 16 + fr) * D2 + kk * 32 + ko];
#pragma unroll
        for (int m = 0; m < 2; ++m)
#pragma unroll
            for (int n = 0; n < 2; ++n)
                acc2[m][n] = __builtin_amdgcn_mfma_f32_16x16x32_bf16(af2[m], bf2[n], acc2[m][n], 0, 0, 0);
    }
#pragma unroll
    for (int n = 0; n < 2; ++n) {
        int col = w * 32 + n * 16 + fr;
        float bv = bq[col];
#pragma unroll
        for (int m = 0; m < 2; ++m)
#pragma unroll
            for (int j = 0; j < 4; ++j) {
                int row = m0 + m * 16 + hi * 4 + j;
                qb[(size_t)row * D2 + col] = (__bf16)(acc2[m][n][j] + bv);
            }
    }
}

// ---------------------------------------------------------------------------
// Fused attention. PASS 1: per-(row, chunk-half) online (max,sumexp) partials,
// slot = ck*2+wc. PASS 2: combine partials in-prologue (rowM/rowInv in LDS),
// recompute S, write exp(S-M)*invL to attn, accumulate col sums.
// ---------------------------------------------------------------------------
template<int PASS>
__global__ __launch_bounds__(256, 2)
void fa_kernel(const __bf16* __restrict__ qbuf, const __bf16* __restrict__ kbuf,
               float* __restrict__ pm, float* __restrict__ pl,
               float* __restrict__ attn, float* __restrict__ colw)
{
    __shared__ __bf16 Kl[2][KTILE * 128];
    __shared__ float rowM_l[QBLK], rowInv_l[QBLK];

    const int t    = threadIdx.x;
    const int lane = t & 63;
    const int w    = t >> 6;
    const int wr   = w >> 1;
    const int wc   = w & 1;
    const int fr   = lane & 15;
    const int hi   = lane >> 4;
    const int ck   = blockIdx.x;
    const int q0   = blockIdx.y * QBLK;
    const int kr0  = ck * KCHUNK;

    stage_tile(qbuf + (size_t)q0 * D2, Kl[0], w, lane);
    __syncthreads();
    bf16x8 af[4][4];
#pragma unroll
    for (int m = 0; m < 4; ++m)
#pragma unroll
        for (int kk = 0; kk < 4; ++kk)
            af[m][kk] = rd_frag(Kl[0], wr * 64 + m * 16 + fr, kk * 4 + hi);

    if constexpr (PASS == 2) {
        // fused combine: rowM/rowInv for this block's 128 rows from 16 slots
        if (t < QBLK) {
            int r = q0 + t;
            float M = -1e30f;
#pragma unroll
            for (int c = 0; c < 2 * NKC; ++c) M = fmaxf(M, pm[(size_t)c * N_TOK + r]);
            float L = 0.0f;
#pragma unroll
            for (int c = 0; c < 2 * NKC; ++c)
                L += pl[(size_t)c * N_TOK + r] * __expf(pm[(size_t)c * N_TOK + r] - M);
            rowM_l[t] = M;
            rowInv_l[t] = 1.0f / L;
        }
    }
    __syncthreads();   // Kl[0] free + rowM_l visible

    float mloc[4][4], lloc[4][4], Mr[4][4], Ir[4][4];
#pragma unroll
    for (int m = 0; m < 4; ++m)
#pragma unroll
        for (int j = 0; j < 4; ++j) {
            if constexpr (PASS == 1) { mloc[m][j] = -1e30f; lloc[m][j] = 0.0f; }
            else {
                int rl = wr * 64 + m * 16 + hi * 4 + j;
                Mr[m][j] = rowM_l[rl]; Ir[m][j] = rowInv_l[rl];
            }
        }

    stage_tile(kbuf + (size_t)kr0 * D2, Kl[0], w, lane);
    __syncthreads();

    for (int kt = 0; kt < KCHUNK / KTILE; ++kt) {
        const __bf16* cur = Kl[kt & 1];
        if (kt + 1 < KCHUNK / KTILE)
            stage_tile(kbuf + (size_t)(kr0 + (kt + 1) * KTILE) * D2, Kl[(kt + 1) & 1], w, lane);

        f32x4 acc[4][4] = {};
#pragma unroll
        for (int kk = 0; kk < 4; ++kk) {
            bf16x8 bfr[4];
#pragma unroll
            for (int n = 0; n < 4; ++n)
                bfr[n] = rd_frag(cur, wc * 64 + n * 16 + fr, kk * 4 + hi);
#pragma unroll
            for (int m = 0; m < 4; ++m)
#pragma unroll
                for (int n = 0; n < 4; ++n)
                    acc[m][n] = __builtin_amdgcn_mfma_f32_16x16x32_bf16(af[m][kk], bfr[n], acc[m][n], 0, 0, 0);
        }

        if constexpr (PASS == 1) {
#pragma unroll
            for (int m = 0; m < 4; ++m)
#pragma unroll
                for (int j = 0; j < 4; ++j) {
                    float a0 = acc[m][0][j], a1 = acc[m][1][j], a2 = acc[m][2][j], a3 = acc[m][3][j];
                    float t4 = fmaxf(fmaxf(a0, a1), fmaxf(a2, a3));
                    float mo = mloc[m][j];
                    float mn = fmaxf(mo, t4);
                    float s  = __expf(a0 - mn) + __expf(a1 - mn) + __expf(a2 - mn) + __expf(a3 - mn);
                    lloc[m][j] = lloc[m][j] * __expf(mo - mn) + s;
                    mloc[m][j] = mn;
                }
        } else {
            float csum[4] = {0.0f, 0.0f, 0.0f, 0.0f};
            const int colbase = kr0 + kt * KTILE + wc * 64;
#pragma unroll
            for (int m = 0; m < 4; ++m) {
#pragma unroll
                for (int n = 0; n < 4; ++n) {
                    int col = colbase + n * 16 + fr;
#pragma unroll
                    for (int j = 0; j < 4; ++j) {
                        int row = q0 + wr * 64 + m * 16 + hi * 4 + j;
                        float p = __expf(acc[m][n][j] - Mr[m][j]) * Ir[m][j];
                        attn[(size_t)row * N_TOK + col] = p;
                        csum[n] += p;
                    }
                }
            }
#pragma unroll
            for (int n = 0; n < 4; ++n) {
                csum[n] += __shfl_xor(csum[n], 16);
                csum[n] += __shfl_xor(csum[n], 32);
            }
            if (lane < 16) {
#pragma unroll
                for (int n = 0; n < 4; ++n)
                    atomicAdd(&colw[colbase + n * 16 + lane], csum[n]);
            }
        }
        __syncthreads();
    }

    if constexpr (PASS == 1) {
        const size_t slot = (size_t)(ck * 2 + wc) * N_TOK;
#pragma unroll
        for (int m = 0; m < 4; ++m)
#pragma unroll
            for (int j = 0; j < 4; ++j) {
                float M = mloc[m][j];
#pragma unroll
                for (int off = 1; off <= 8; off <<= 1) M = fmaxf(M, __shfl_xor(M, off));
                float l = lloc[m][j] * __expf(mloc[m][j] - M);
#pragma unroll
                for (int off = 1; off <= 8; off <<= 1) l += __shfl_xor(l, off);
                if ((lane & 15) == 0) {
                    int r = q0 + wr * 64 + m * 16 + hi * 4 + j;
                    pm[slot + r] = M;
                    pl[slot + r] = l;
                }
            }
    }
}

// xw[c] = sum_m colw[m]*h2[m,c] ; xh[c] = sum_m h2[m,c]
__global__ __launch_bounds__(256)
void reduce_x2(const __bf16* __restrict__ h2b, const float* __restrict__ colw,
               float* __restrict__ xw, float* __restrict__ xh) {
    int b = blockIdx.x, t = threadIdx.x;
    int c = t & 127, half = t >> 7;
    float aw = 0.0f, ah = 0.0f;
    for (int m = b * 128 + half; m < (b + 1) * 128; m += 2) {
        float h  = (float)h2b[(size_t)m * D2 + c];
        float wv = colw[m];
        aw += wv * h;
        ah += h;
    }
    atomicAdd(&xw[c], aw);
    atomicAdd(&xh[c], ah);
}

__global__ void logits_k(const float* __restrict__ xw, const float* __restrict__ xh,
                         const float* __restrict__ gamma, const float* __restrict__ W3,
                         const float* __restrict__ b3, float* __restrict__ out) {
    __shared__ float x2[D2];
    int t = threadIdx.x;
    float g = gamma[0];
    if (t < D2) x2[t] = (g * xw[t] + xh[t]) * (1.0f / (float)N_TOK);
    __syncthreads();
    if (t < 10) {
        float s = b3[t];
        for (int c = 0; c < D2; ++c) s += x2[c] * W3[t * D2 + c];
        out[t] = s;
    }
}

// ---------------------------------------------------------------------------
extern "C" void kernel_launch(void* const* d_in, const int* in_sizes, int n_in,
                              void* d_out, int out_size, void* d_ws, size_t ws_size,
                              hipStream_t stream) {
    const float* x     = (const float*)d_in[0];
    const float* W1    = (const float*)d_in[1];
    const float* b1    = (const float*)d_in[2];
    const float* W2    = (const float*)d_in[3];
    const float* b2    = (const float*)d_in[4];
    const float* Wq    = (const float*)d_in[5];
    const float* bq    = (const float*)d_in[6];
    const float* Wk    = (const float*)d_in[7];
    const float* bk    = (const float*)d_in[8];
    const float* gamma = (const float*)d_in[9];
    const float* W3    = (const float*)d_in[10];
    const float* b3    = (const float*)d_in[11];

    float* out  = (float*)d_out;
    float* attn = out + 10;            // 8192x8192 f32

    char* p = (char*)d_ws;
    __bf16* w1b = (__bf16*)p; p += (size_t)D1 * IN_FEAT * 2;
    __bf16* w2b = (__bf16*)p; p += (size_t)D2 * D1 * 2;
    __bf16* wqb = (__bf16*)p; p += (size_t)D2 * D2 * 2;
    __bf16* h1b = (__bf16*)p; p += (size_t)N_TOK * D1 * 2;
    __bf16* h2b = (__bf16*)p; p += (size_t)N_TOK * D2 * 2;
    __bf16* qb  = (__bf16*)p; p += (size_t)N_TOK * D2 * 2;
    __bf16* kb  = (__bf16*)p; p += (size_t)N_TOK * D2 * 2;
    float* pm     = (float*)p; p += (size_t)2 * NKC * N_TOK * 4;
    float* pl     = (float*)p; p += (size_t)2 * NKC * N_TOK * 4;
    float* colw   = (float*)p; p += N_TOK * 4;
    float* wksum  = (float*)p; p += D2 * 4;
    float* xw     = (float*)p; p += D2 * 4;
    float* xh     = (float*)p; p += D2 * 4;

    prep<<<1137, 256, 0, stream>>>(W1, w1b, W2, w2b, Wq, wqb, Wk, wksum, colw, xw, xh);

    gemm1_k<<<512, 256, 0, stream>>>(x, w1b, b1, h1b);
    mlp2_k<<<N_TOK / 32, 256, 0, stream>>>(h1b, w2b, b2, wqb, bq, wksum, bk, h2b, kb, qb);

    fa_kernel<1><<<dim3(NKC, NQB), 256, 0, stream>>>(qb, kb, pm, pl, nullptr, nullptr);
    fa_kernel<2><<<dim3(NKC, NQB), 256, 0, stream>>>(qb, kb, pm, pl, attn, colw);

    reduce_x2<<<64, 256, 0, stream>>>(h2b, colw, xw, xh);
    logits_k<<<1, 128, 0, stream>>>(xw, xh, gamma, W3, b3, out);
}

// Round 7
// 254.757 us; speedup vs baseline: 1.6755x; 1.1482x over previous
//
#include <hip/hip_runtime.h>
#include <hip/hip_bf16.h>

typedef __attribute__((ext_vector_type(8))) __bf16 bf16x8;
typedef __attribute__((ext_vector_type(4))) __bf16 bf16x4;
typedef __attribute__((ext_vector_type(4))) float f32x4;

#define N_TOK 8192
#define IN_FEAT 2048
#define D1 512
#define D2 128
#define QBLK 128
#define KCHUNK 1024
#define KTILE 128
#define NKC (N_TOK / KCHUNK)   // 8
#define NQB (N_TOK / QBLK)     // 64
#define LOG2E 1.44269504f

__device__ __forceinline__ float fexp2(float x) {
    float r;
    asm("v_exp_f32 %0, %1" : "=v"(r) : "v"(x));
    return r;
}

__device__ __forceinline__ void gload_lds16(const __bf16* g, __bf16* l) {
    __builtin_amdgcn_global_load_lds(
        (const __attribute__((address_space(1))) void*)g,
        (__attribute__((address_space(3))) void*)l,
        16, 0, 0);
}

// ---------------------------------------------------------------------------
// prep: fused weight casts + wksum + accumulator zeros (one launch)
// ---------------------------------------------------------------------------
__global__ __launch_bounds__(256)
void prep(const float* __restrict__ W1, __bf16* __restrict__ w1b,
          const float* __restrict__ W2, __bf16* __restrict__ w2b,
          const float* __restrict__ Wq, __bf16* __restrict__ wqb,
          const float* __restrict__ Wk, float* __restrict__ wksum,
          float* __restrict__ colw, float* __restrict__ xw, float* __restrict__ xh) {
    int b = blockIdx.x, t = threadIdx.x;
    const float* src = nullptr; __bf16* dst = nullptr; int i = 0;
    if (b < 1024)      { src = W1; dst = w1b; i = b * 256 + t; }
    else if (b < 1088) { src = W2; dst = w2b; i = (b - 1024) * 256 + t; }
    else if (b < 1104) { src = Wq; dst = wqb; i = (b - 1088) * 256 + t; }
    else if (b < 1136) { colw[(b - 1104) * 256 + t] = 0.0f; return; }
    else {
        if (t < D2) {
            float s = 0.0f;
            for (int o = 0; o < D2; ++o) s += Wk[o * D2 + t];
            wksum[t] = s;
            xw[t] = 0.0f; xh[t] = 0.0f;
        }
        return;
    }
    float4 v = ((const float4*)src)[i];
    bf16x4 o;
    o[0] = (__bf16)v.x; o[1] = (__bf16)v.y; o[2] = (__bf16)v.z; o[3] = (__bf16)v.w;
    ((bf16x4*)dst)[i] = o;
}

// ---------------------------------------------------------------------------
// gemm1: h1 = relu(x @ W1^T + b1). A f32 reg-staged + prefetch. BM=128 BN=64.
// 1D grid 512; decode y=b&63, x=b>>6 -> the 8 n-blocks sharing an x-strip
// land on the SAME XCD (b%8 equal) -> x streams through one L2 (T1).
// ---------------------------------------------------------------------------
__global__ __launch_bounds__(256)
void gemm1_k(const float* __restrict__ x, const __bf16* __restrict__ w1b,
             const float* __restrict__ b1, __bf16* __restrict__ h1b) {
    __shared__ __bf16 lA[128 * 32];
    __shared__ __bf16 lB[64 * 32];

    const int t    = threadIdx.x;
    const int lane = t & 63;
    const int w    = t >> 6;
    const int wr   = w >> 1;
    const int wc   = w & 1;
    const int b    = blockIdx.x;
    const int m0   = (b & 63) * 128;
    const int n0   = (b >> 6) * 64;

    const int rS = w * 16 + (lane >> 2);
    const int cS = (lane & 3) * 8;
    const int fr = lane & 15;
    const int hi = lane >> 4;
    const int ko = hi * 8;
    const int rj = hi * 4;

    const int ar = t >> 3;
    const int ac = (t & 7) * 4;

    f32x4 acc[4][2] = {};

    float4 regs[4];
#pragma unroll
    for (int i = 0; i < 4; ++i)
        regs[i] = *(const float4*)&x[(size_t)(m0 + i * 32 + ar) * IN_FEAT + ac];

    for (int k0 = 0; k0 < IN_FEAT; k0 += 32) {
        __syncthreads();
#pragma unroll
        for (int i = 0; i < 4; ++i) {
            bf16x4 o;
            o[0] = (__bf16)regs[i].x; o[1] = (__bf16)regs[i].y;
            o[2] = (__bf16)regs[i].z; o[3] = (__bf16)regs[i].w;
            *(bf16x4*)&lA[(i * 32 + ar) * 32 + ac] = o;
        }
        gload_lds16(w1b + (size_t)(n0 + rS) * IN_FEAT + k0 + cS, lB + w * 512);
        __syncthreads();

        if (k0 + 32 < IN_FEAT) {
#pragma unroll
            for (int i = 0; i < 4; ++i)
                regs[i] = *(const float4*)&x[(size_t)(m0 + i * 32 + ar) * IN_FEAT + k0 + 32 + ac];
        }

        bf16x8 af[4], bf[2];
#pragma unroll
        for (int m = 0; m < 4; ++m)
            af[m] = *(const bf16x8*)&lA[(wr * 64 + m * 16 + fr) * 32 + ko];
#pragma unroll
        for (int n = 0; n < 2; ++n)
            bf[n] = *(const bf16x8*)&lB[(wc * 32 + n * 16 + fr) * 32 + ko];
#pragma unroll
        for (int m = 0; m < 4; ++m)
#pragma unroll
            for (int n = 0; n < 2; ++n)
                acc[m][n] = __builtin_amdgcn_mfma_f32_16x16x32_bf16(af[m], bf[n], acc[m][n], 0, 0, 0);
    }

#pragma unroll
    for (int n = 0; n < 2; ++n) {
        int col = n0 + wc * 32 + n * 16 + fr;
        float bv = b1[col];
#pragma unroll
        for (int m = 0; m < 4; ++m) {
            int row = m0 + wr * 64 + m * 16 + rj;
#pragma unroll
            for (int j = 0; j < 4; ++j)
                h1b[(size_t)(row + j) * D1 + col] = (__bf16)fmaxf(acc[m][n][j] + bv, 0.0f);
        }
    }
}

// ---------------------------------------------------------------------------
// mlp2: per 32-row block: h2 = relu(h1 @ W2^T + b2) -> h2b, kb (col-scale),
// q = (h2 @ Wq^T + bq) * LOG2E -> qb  (base-2 softmax domain).
// ---------------------------------------------------------------------------
__global__ __launch_bounds__(256)
void mlp2_k(const __bf16* __restrict__ h1b, const __bf16* __restrict__ w2b,
            const float* __restrict__ b2, const __bf16* __restrict__ wqb,
            const float* __restrict__ bq, const float* __restrict__ wksum,
            const float* __restrict__ bk, __bf16* __restrict__ h2b,
            __bf16* __restrict__ kb, __bf16* __restrict__ qb) {
    __shared__ __bf16 lA[32 * 32];
    __shared__ __bf16 lB[128 * 32];
    __shared__ __bf16 lH[32 * 128];

    const int t    = threadIdx.x;
    const int lane = t & 63;
    const int w    = t >> 6;
    const int fr   = lane & 15;
    const int hi   = lane >> 4;
    const int ko   = hi * 8;
    const int m0   = blockIdx.x * 32;

    f32x4 acc[2][2] = {};

    for (int k0 = 0; k0 < D1; k0 += 32) {
        __syncthreads();
        if (w < 2)
            gload_lds16(h1b + (size_t)(m0 + w * 16 + (lane >> 2)) * D1 + k0 + (lane & 3) * 8,
                        lA + w * 512);
#pragma unroll
        for (int i = 0; i < 2; ++i) {
            int row = w * 32 + i * 16 + (lane >> 2);
            gload_lds16(w2b + (size_t)row * D1 + k0 + (lane & 3) * 8,
                        lB + w * 1024 + i * 512);
        }
        __syncthreads();

        bf16x8 af[2], bf[2];
#pragma unroll
        for (int m = 0; m < 2; ++m)
            af[m] = *(const bf16x8*)&lA[(m * 16 + fr) * 32 + ko];
#pragma unroll
        for (int n = 0; n < 2; ++n)
            bf[n] = *(const bf16x8*)&lB[(w * 32 + n * 16 + fr) * 32 + ko];
#pragma unroll
        for (int m = 0; m < 2; ++m)
#pragma unroll
            for (int n = 0; n < 2; ++n)
                acc[m][n] = __builtin_amdgcn_mfma_f32_16x16x32_bf16(af[m], bf[n], acc[m][n], 0, 0, 0);
    }

#pragma unroll
    for (int n = 0; n < 2; ++n) {
        int col = w * 32 + n * 16 + fr;
        float bv = b2[col], wv = wksum[col], bkv = bk[col];
#pragma unroll
        for (int m = 0; m < 2; ++m) {
#pragma unroll
            for (int j = 0; j < 4; ++j) {
                int row = m * 16 + hi * 4 + j;
                float v = fmaxf(acc[m][n][j] + bv, 0.0f);
                h2b[(size_t)(m0 + row) * D2 + col] = (__bf16)v;
                kb [(size_t)(m0 + row) * D2 + col] = (__bf16)(wv * v + bkv);
                lH[row * 128 + (((col >> 3) ^ (row & 7)) * 8) + (col & 7)] = (__bf16)v;
            }
        }
    }
    __syncthreads();

    f32x4 acc2[2][2] = {};
#pragma unroll
    for (int kk = 0; kk < 4; ++kk) {
        bf16x8 af2[2], bf2[2];
#pragma unroll
        for (int m = 0; m < 2; ++m) {
            int row = m * 16 + fr;
            af2[m] = *(const bf16x8*)&lH[row * 128 + (((kk * 4 + hi) ^ (row & 7)) * 8)];
        }
#pragma unroll
        for (int n = 0; n < 2; ++n)
            bf2[n] = *(const bf16x8*)&wqb[(size_t)(w * 32 + n * 16 + fr) * D2 + kk * 32 + ko];
#pragma unroll
        for (int m = 0; m < 2; ++m)
#pragma unroll
            for (int n = 0; n < 2; ++n)
                acc2[m][n] = __builtin_amdgcn_mfma_f32_16x16x32_bf16(af2[m], bf2[n], acc2[m][n], 0, 0, 0);
    }
#pragma unroll
    for (int n = 0; n < 2; ++n) {
        int col = w * 32 + n * 16 + fr;
        float bv = bq[col];
#pragma unroll
        for (int m = 0; m < 2; ++m)
#pragma unroll
            for (int j = 0; j < 4; ++j) {
                int row = m0 + m * 16 + hi * 4 + j;
                qb[(size_t)row * D2 + col] = (__bf16)((acc2[m][n][j] + bv) * LOG2E);
            }
    }
}

// ---------------------------------------------------------------------------
// Fused attention, ALL fragment loads direct from global (qb/kb are 2 MB:
// L2-resident; LDS staging of L2-fit data is pure overhead -> no K LDS,
// no per-kt barriers). Base-2 softmax domain (q pre-scaled by log2e).
// PASS 1: per-(row, chunk-half) online (max,sum2) partials, slot = ck*2+wc,
//         defer-max (T13, THR=11.5 in base-2).
// PASS 2: combine partials in prologue, recompute S, attn = 2^(S-M)*invL,
//         accumulate column sums.
// ---------------------------------------------------------------------------
template<int PASS>
__global__ __launch_bounds__(256, 2)
void fa_kernel(const __bf16* __restrict__ qbuf, const __bf16* __restrict__ kbuf,
               float* __restrict__ pm, float* __restrict__ pl,
               float* __restrict__ attn, float* __restrict__ colw)
{
    __shared__ float rowM_l[QBLK], rowInv_l[QBLK];

    const int t    = threadIdx.x;
    const int lane = t & 63;
    const int w    = t >> 6;
    const int wr   = w >> 1;
    const int wc   = w & 1;
    const int fr   = lane & 15;
    const int hi   = lane >> 4;
    const int ck   = blockIdx.x;
    const int q0   = blockIdx.y * QBLK;
    const int kr0  = ck * KCHUNK;

    // Q fragments straight from L2
    bf16x8 af[4][4];
#pragma unroll
    for (int m = 0; m < 4; ++m)
#pragma unroll
        for (int kk = 0; kk < 4; ++kk)
            af[m][kk] = *(const bf16x8*)&qbuf[(size_t)(q0 + wr * 64 + m * 16 + fr) * D2 + kk * 32 + hi * 8];

    float mloc[4][4], lloc[4][4], Mr[4][4], Ir[4][4];
    if constexpr (PASS == 2) {
        if (t < QBLK) {
            int r = q0 + t;
            float M = -1e30f;
#pragma unroll
            for (int c = 0; c < 2 * NKC; ++c) M = fmaxf(M, pm[(size_t)c * N_TOK + r]);
            float L = 0.0f;
#pragma unroll
            for (int c = 0; c < 2 * NKC; ++c)
                L += pl[(size_t)c * N_TOK + r] * fexp2(pm[(size_t)c * N_TOK + r] - M);
            rowM_l[t] = M;
            rowInv_l[t] = 1.0f / L;
        }
        __syncthreads();
#pragma unroll
        for (int m = 0; m < 4; ++m)
#pragma unroll
            for (int j = 0; j < 4; ++j) {
                int rl = wr * 64 + m * 16 + hi * 4 + j;
                Mr[m][j] = rowM_l[rl]; Ir[m][j] = rowInv_l[rl];
            }
    } else {
#pragma unroll
        for (int m = 0; m < 4; ++m)
#pragma unroll
            for (int j = 0; j < 4; ++j) { mloc[m][j] = -1e30f; lloc[m][j] = 0.0f; }
    }

    const __bf16* kbase = kbuf + (size_t)(kr0 + wc * 64 + fr) * D2 + hi * 8;

#pragma unroll 1
    for (int kt = 0; kt < KCHUNK / KTILE; ++kt) {
        const __bf16* kp = kbase + (size_t)kt * KTILE * D2;

        f32x4 acc[4][4] = {};
#pragma unroll
        for (int kk = 0; kk < 4; ++kk) {
            bf16x8 bfr[4];
#pragma unroll
            for (int n = 0; n < 4; ++n)
                bfr[n] = *(const bf16x8*)&kp[(size_t)n * 16 * D2 + kk * 32];
#pragma unroll
            for (int m = 0; m < 4; ++m)
#pragma unroll
                for (int n = 0; n < 4; ++n)
                    acc[m][n] = __builtin_amdgcn_mfma_f32_16x16x32_bf16(af[m][kk], bfr[n], acc[m][n], 0, 0, 0);
        }

        if constexpr (PASS == 1) {
#pragma unroll
            for (int m = 0; m < 4; ++m)
#pragma unroll
                for (int j = 0; j < 4; ++j) {
                    float a0 = acc[m][0][j], a1 = acc[m][1][j], a2 = acc[m][2][j], a3 = acc[m][3][j];
                    float t4 = fmaxf(fmaxf(a0, a1), fmaxf(a2, a3));
                    if (!__all(t4 <= mloc[m][j] + 11.5f)) {   // T13 defer-max
                        float mn = fmaxf(mloc[m][j], t4);
                        lloc[m][j] *= fexp2(mloc[m][j] - mn);
                        mloc[m][j] = mn;
                    }
                    float mo = mloc[m][j];
                    lloc[m][j] += fexp2(a0 - mo) + fexp2(a1 - mo) + fexp2(a2 - mo) + fexp2(a3 - mo);
                }
        } else {
            float csum[4] = {0.0f, 0.0f, 0.0f, 0.0f};
            const int colbase = kr0 + kt * KTILE + wc * 64;
#pragma unroll
            for (int m = 0; m < 4; ++m) {
#pragma unroll
                for (int n = 0; n < 4; ++n) {
                    int col = colbase + n * 16 + fr;
#pragma unroll
                    for (int j = 0; j < 4; ++j) {
                        int row = q0 + wr * 64 + m * 16 + hi * 4 + j;
                        float p = fexp2(acc[m][n][j] - Mr[m][j]) * Ir[m][j];
                        attn[(size_t)row * N_TOK + col] = p;
                        csum[n] += p;
                    }
                }
            }
#pragma unroll
            for (int n = 0; n < 4; ++n) {
                csum[n] += __shfl_xor(csum[n], 16);
                csum[n] += __shfl_xor(csum[n], 32);
            }
            if (lane < 16) {
#pragma unroll
                for (int n = 0; n < 4; ++n)
                    atomicAdd(&colw[colbase + n * 16 + lane], csum[n]);
            }
        }
    }

    if constexpr (PASS == 1) {
        const size_t slot = (size_t)(ck * 2 + wc) * N_TOK;
#pragma unroll
        for (int m = 0; m < 4; ++m)
#pragma unroll
            for (int j = 0; j < 4; ++j) {
                float M = mloc[m][j];
#pragma unroll
                for (int off = 1; off <= 8; off <<= 1) M = fmaxf(M, __shfl_xor(M, off));
                float l = lloc[m][j] * fexp2(mloc[m][j] - M);
#pragma unroll
                for (int off = 1; off <= 8; off <<= 1) l += __shfl_xor(l, off);
                if ((lane & 15) == 0) {
                    int r = q0 + wr * 64 + m * 16 + hi * 4 + j;
                    pm[slot + r] = M;
                    pl[slot + r] = l;
                }
            }
    }
}

// xw[c] = sum_m colw[m]*h2[m,c] ; xh[c] = sum_m h2[m,c]
__global__ __launch_bounds__(256)
void reduce_x2(const __bf16* __restrict__ h2b, const float* __restrict__ colw,
               float* __restrict__ xw, float* __restrict__ xh) {
    int b = blockIdx.x, t = threadIdx.x;
    int c = t & 127, half = t >> 7;
    float aw = 0.0f, ah = 0.0f;
    for (int m = b * 128 + half; m < (b + 1) * 128; m += 2) {
        float h  = (float)h2b[(size_t)m * D2 + c];
        float wv = colw[m];
        aw += wv * h;
        ah += h;
    }
    atomicAdd(&xw[c], aw);
    atomicAdd(&xh[c], ah);
}

__global__ void logits_k(const float* __restrict__ xw, const float* __restrict__ xh,
                         const float* __restrict__ gamma, const float* __restrict__ W3,
                         const float* __restrict__ b3, float* __restrict__ out) {
    __shared__ float x2[D2];
    int t = threadIdx.x;
    float g = gamma[0];
    if (t < D2) x2[t] = (g * xw[t] + xh[t]) * (1.0f / (float)N_TOK);
    __syncthreads();
    if (t < 10) {
        float s = b3[t];
        for (int c = 0; c < D2; ++c) s += x2[c] * W3[t * D2 + c];
        out[t] = s;
    }
}

// ---------------------------------------------------------------------------
extern "C" void kernel_launch(void* const* d_in, const int* in_sizes, int n_in,
                              void* d_out, int out_size, void* d_ws, size_t ws_size,
                              hipStream_t stream) {
    const float* x     = (const float*)d_in[0];
    const float* W1    = (const float*)d_in[1];
    const float* b1    = (const float*)d_in[2];
    const float* W2    = (const float*)d_in[3];
    const float* b2    = (const float*)d_in[4];
    const float* Wq    = (const float*)d_in[5];
    const float* bq    = (const float*)d_in[6];
    const float* Wk    = (const float*)d_in[7];
    const float* bk    = (const float*)d_in[8];
    const float* gamma = (const float*)d_in[9];
    const float* W3    = (const float*)d_in[10];
    const float* b3    = (const float*)d_in[11];

    float* out  = (float*)d_out;
    float* attn = out + 10;            // 8192x8192 f32

    char* p = (char*)d_ws;
    __bf16* w1b = (__bf16*)p; p += (size_t)D1 * IN_FEAT * 2;
    __bf16* w2b = (__bf16*)p; p += (size_t)D2 * D1 * 2;
    __bf16* wqb = (__bf16*)p; p += (size_t)D2 * D2 * 2;
    __bf16* h1b = (__bf16*)p; p += (size_t)N_TOK * D1 * 2;
    __bf16* h2b = (__bf16*)p; p += (size_t)N_TOK * D2 * 2;
    __bf16* qb  = (__bf16*)p; p += (size_t)N_TOK * D2 * 2;
    __bf16* kb  = (__bf16*)p; p += (size_t)N_TOK * D2 * 2;
    float* pm     = (float*)p; p += (size_t)2 * NKC * N_TOK * 4;
    float* pl     = (float*)p; p += (size_t)2 * NKC * N_TOK * 4;
    float* colw   = (float*)p; p += N_TOK * 4;
    float* wksum  = (float*)p; p += D2 * 4;
    float* xw     = (float*)p; p += D2 * 4;
    float* xh     = (float*)p; p += D2 * 4;

    prep<<<1137, 256, 0, stream>>>(W1, w1b, W2, w2b, Wq, wqb, Wk, wksum, colw, xw, xh);

    gemm1_k<<<512, 256, 0, stream>>>(x, w1b, b1, h1b);
    mlp2_k<<<N_TOK / 32, 256, 0, stream>>>(h1b, w2b, b2, wqb, bq, wksum, bk, h2b, kb, qb);

    fa_kernel<1><<<dim3(NKC, NQB), 256, 0, stream>>>(qb, kb, pm, pl, nullptr, nullptr);
    fa_kernel<2><<<dim3(NKC, NQB), 256, 0, stream>>>(qb, kb, pm, pl, attn, colw);

    reduce_x2<<<64, 256, 0, stream>>>(h2b, colw, xw, xh);
    logits_k<<<1, 128, 0, stream>>>(xw, xh, gamma, W3, b3, out);
}